// Round 1
// baseline (6259.608 us; speedup 1.0000x reference)
//
#include <hip/hip_runtime.h>
#include <math.h>

#define N_SAMP 8192
#define LAT 16
#define DID 8
#define DTR 8
#define KB 8          // NBINS
#define CTXD 256
#define HIDD 256
#define NRES 2
#define NBLK 8
#define PDIM 184      // DTR*(3*KB-1)
#define TAILF 3.0f

__device__ __forceinline__ float softplusf(float x){
  return (x > 20.0f) ? x : log1pf(expf(x));
}

// Inverse rational-quadratic spline with linear tails (nflows convention),
// K=8 bins. uw,uh: 8 raw params; ud: 7 interior raw derivatives.
__device__ __forceinline__ void rqs_inv1(float x, const float* uw, const float* uh,
                                         const float* ud, float* outp, float* nladp)
{
  const float T = TAILF;
  bool inside = (x >= -T) && (x <= T);

  float cw[KB+1], wv[KB], ch[KB+1], hv[KB], dv[KB+1];
  // widths
  {
    float m = uw[0];
    #pragma unroll
    for (int k=1;k<KB;k++) m = fmaxf(m, uw[k]);
    float e[KB]; float ssum = 0.f;
    #pragma unroll
    for (int k=0;k<KB;k++){ e[k] = expf(uw[k]-m); ssum += e[k]; }
    float inv = 1.f/ssum;
    float c = 0.f;
    cw[0] = -T;
    #pragma unroll
    for (int k=0;k<KB;k++){
      c += 0.001f + (1.f - 0.001f*KB)*e[k]*inv;
      cw[k+1] = 2.f*T*c - T;
    }
    cw[KB] = T;
    #pragma unroll
    for (int k=0;k<KB;k++) wv[k] = cw[k+1]-cw[k];
  }
  // heights
  {
    float m = uh[0];
    #pragma unroll
    for (int k=1;k<KB;k++) m = fmaxf(m, uh[k]);
    float e[KB]; float ssum = 0.f;
    #pragma unroll
    for (int k=0;k<KB;k++){ e[k] = expf(uh[k]-m); ssum += e[k]; }
    float inv = 1.f/ssum;
    float c = 0.f;
    ch[0] = -T;
    #pragma unroll
    for (int k=0;k<KB;k++){
      c += 0.001f + (1.f - 0.001f*KB)*e[k]*inv;
      ch[k+1] = 2.f*T*c - T;
    }
    ch[KB] = T;
    #pragma unroll
    for (int k=0;k<KB;k++) hv[k] = ch[k+1]-ch[k];
  }
  // derivatives: padded ends give exactly MIND + softplus(DCONST) = 1.0
  dv[0] = 1.f; dv[KB] = 1.f;
  #pragma unroll
  for (int k=0;k<KB-1;k++) dv[k+1] = 0.001f + softplusf(ud[k]);

  float xc = fminf(fmaxf(x, -T), T);
  // bin search against ch knots (inverse: x lives in y-space)
  int cnt = 0;
  #pragma unroll
  for (int k=0;k<=KB;k++){
    float thr = ch[k] + (k==KB ? 1e-6f : 0.f);
    cnt += (xc >= thr) ? 1 : 0;
  }
  int idx = cnt - 1;
  idx = idx < 0 ? 0 : (idx > KB-1 ? KB-1 : idx);

  // take() via unrolled selects (avoid dynamic local indexing -> scratch)
  float icw=cw[0], iw=wv[0], ich=ch[0], ih=hv[0], d0=dv[0], d1=dv[1];
  #pragma unroll
  for (int k=1;k<KB;k++){
    bool sel = (idx==k);
    icw = sel?cw[k]:icw; iw = sel?wv[k]:iw; ich = sel?ch[k]:ich;
    ih = sel?hv[k]:ih; d0 = sel?dv[k]:d0; d1 = sel?dv[k+1]:d1;
  }

  float delta = ih/iw;
  float sq = d0 + d1 - 2.f*delta;
  float yv = xc - ich;
  float aa = yv*sq + ih*(delta-d0);
  float bb = ih*d0 - yv*sq;
  float cc = -delta*yv;
  float disc = fmaxf(bb*bb - 4.f*aa*cc, 0.f);
  float root = 2.f*cc / (-bb - sqrtf(disc));
  float o = root*iw + icw;
  float t1m = root*(1.f-root);
  float den = delta + sq*t1m;
  float num = delta*delta*(d1*root*root + 2.f*delta*t1m + d0*(1.f-root)*(1.f-root));
  float lad = logf(num) - 2.f*logf(den);
  *outp = inside ? o : x;
  *nladp = inside ? -lad : 0.f;
}

__global__ __launch_bounds__(256) void init_k(const float* __restrict__ x,
                                              float* __restrict__ z,
                                              float* __restrict__ logdet)
{
  int i = blockIdx.x*256 + threadIdx.x;
  if (i < N_SAMP*LAT) z[i] = x[i];
  if (i < N_SAMP) logdet[i] = 0.f;
}

// Per-sample: permute, LU-linear (z <- L U z + b), logdet += sum log diag,
// uncond RQS-inverse on even dims -> zid; odd dims -> ztr.
__global__ __launch_bounds__(256) void pre_k(
  const float* __restrict__ z, float* __restrict__ zid, float* __restrict__ ztr,
  float* __restrict__ logdet,
  const float* __restrict__ lu_lower, const float* __restrict__ lu_upper,
  const float* __restrict__ lu_udiag, const float* __restrict__ lu_bias,
  const float* __restrict__ ucw, const float* __restrict__ uch,
  const float* __restrict__ ucd, const int* __restrict__ perm)
{
  int n = blockIdx.x*256 + threadIdx.x;
  if (n >= N_SAMP) return;

  float zin[LAT];
  #pragma unroll
  for (int j=0;j<LAT;j++) zin[j] = z[n*LAT + perm[j]];

  float ldet = 0.f;
  float y[LAT];
  #pragma unroll
  for (int r=0;r<LAT;r++){
    float dg = softplusf(lu_udiag[r]) + 0.001f;
    ldet += logf(dg);
    float acc = dg * zin[r];
    #pragma unroll
    for (int c=r+1;c<LAT;c++){
      int t = r*15 - (r*(r-1))/2 + (c-r-1);   // triu row-major index
      acc += lu_upper[t]*zin[c];
    }
    y[r] = acc;
  }
  float wv[LAT];
  #pragma unroll
  for (int r=0;r<LAT;r++){
    float acc = y[r] + lu_bias[r];
    #pragma unroll
    for (int c=0;c<r;c++){
      acc += lu_lower[(r*(r-1))/2 + c]*y[c];  // tril row-major index
    }
    wv[r] = acc;
  }

  #pragma unroll
  for (int k=0;k<DID;k++){
    float uwv[KB], uhv[KB], udv[KB-1];
    #pragma unroll
    for (int b=0;b<KB;b++){ uwv[b]=ucw[k*KB+b]; uhv[b]=uch[k*KB+b]; }
    #pragma unroll
    for (int b=0;b<KB-1;b++) udv[b]=ucd[k*(KB-1)+b];
    float o, nl;
    rqs_inv1(wv[2*k], uwv, uhv, udv, &o, &nl);
    zid[n*DID+k] = o;
    ztr[n*DID+k] = wv[2*k+1];
    ldet += nl;
  }
  logdet[n] += ldet;
}

// ---------------- f32 tiled GEMM: C[r][m] = sum_k A'(r,k) * W[k][m] (+epilogue)
// AMODE: 0 = plain A0, 1 = relu(A0), 2 = concat(zid[8], ctx[256])
// EPI:   0 = Cout = acc + bias
//        1 = dual GEMM: Cout += (acc + bias) * sigmoid(accg + bg), accg = ctx@Wg
#define BM 64
#define BN 64
#define BKT 32

template<int AMODE>
__device__ __forceinline__ float loadAelem(const float* A0, int lda0,
                                           const float* ctxp, int r, int k, int Kdim)
{
  if (k >= Kdim) return 0.f;
  if constexpr (AMODE==0) return A0[r*lda0+k];
  else if constexpr (AMODE==1) return fmaxf(A0[r*lda0+k], 0.f);
  else return (k<DID) ? A0[r*DID+k] : ctxp[r*CTXD + (k-DID)];
}

template<int AMODE, int EPI>
__global__ __launch_bounds__(256) void gemm_k(
  const float* __restrict__ A0, int lda0,
  const float* __restrict__ ctxp,
  const float* __restrict__ W, const float* __restrict__ bias,
  const float* __restrict__ Wg, const float* __restrict__ bg,
  float* __restrict__ Cout, int ldc, int Kdim, int Mdim)
{
  __shared__ float As[BM][BKT+1];
  __shared__ float Bs[BKT][BN+1];
  __shared__ float As2[(EPI==1)?BM:1][BKT+1];
  __shared__ float Bs2[(EPI==1)?BKT:1][BN+1];

  const int tid = threadIdx.x;
  const int tx = tid & 15, ty = tid >> 4;
  const int bm = blockIdx.y * BM;
  const int bn = blockIdx.x * BN;

  float acc[4][4];
  float accg[4][4];
  #pragma unroll
  for (int i=0;i<4;i++)
    #pragma unroll
    for (int j=0;j<4;j++){ acc[i][j]=0.f; if (EPI==1) accg[i][j]=0.f; }

  for (int k0 = 0; k0 < Kdim; k0 += BKT) {
    #pragma unroll
    for (int q=0;q<8;q++){
      int e = q*256 + tid;
      int r = e >> 5, kk = e & 31;
      As[r][kk] = loadAelem<AMODE>(A0, lda0, ctxp, bm+r, k0+kk, Kdim);
    }
    #pragma unroll
    for (int q=0;q<8;q++){
      int e = q*256 + tid;
      int kk = e >> 6, m = e & 63;
      int kg = k0+kk;
      Bs[kk][m] = (kg < Kdim && bn+m < Mdim) ? W[kg*Mdim + bn + m] : 0.f;
    }
    if constexpr (EPI==1) {
      #pragma unroll
      for (int q=0;q<8;q++){
        int e = q*256 + tid;
        int r = e >> 5, kk = e & 31;
        As2[r][kk] = loadAelem<0>(ctxp, CTXD, nullptr, bm+r, k0+kk, Kdim);
      }
      #pragma unroll
      for (int q=0;q<8;q++){
        int e = q*256 + tid;
        int kk = e >> 6, m = e & 63;
        int kg = k0+kk;
        Bs2[kk][m] = (kg < Kdim && bn+m < Mdim) ? Wg[kg*Mdim + bn + m] : 0.f;
      }
    }
    __syncthreads();

    #pragma unroll
    for (int kk=0; kk<BKT; kk++){
      float a[4], b[4];
      #pragma unroll
      for (int i=0;i<4;i++) a[i] = As[ty*4+i][kk];
      #pragma unroll
      for (int j=0;j<4;j++) b[j] = Bs[kk][tx*4+j];
      #pragma unroll
      for (int i=0;i<4;i++)
        #pragma unroll
        for (int j=0;j<4;j++) acc[i][j] = fmaf(a[i], b[j], acc[i][j]);
      if constexpr (EPI==1){
        float a2[4], b2[4];
        #pragma unroll
        for (int i=0;i<4;i++) a2[i] = As2[ty*4+i][kk];
        #pragma unroll
        for (int j=0;j<4;j++) b2[j] = Bs2[kk][tx*4+j];
        #pragma unroll
        for (int i=0;i<4;i++)
          #pragma unroll
          for (int j=0;j<4;j++) accg[i][j] = fmaf(a2[i], b2[j], accg[i][j]);
      }
    }
    __syncthreads();
  }

  #pragma unroll
  for (int i=0;i<4;i++){
    int r = bm + ty*4 + i;
    #pragma unroll
    for (int j=0;j<4;j++){
      int m = bn + tx*4 + j;
      if (m < Mdim){
        if constexpr (EPI==0){
          Cout[r*ldc + m] = acc[i][j] + bias[m];
        } else {
          float v = acc[i][j] + bias[m];
          float g = accg[i][j] + bg[m];
          float sg = 1.f/(1.f + expf(-g));
          Cout[r*ldc + m] += v * sg;
        }
      }
    }
  }
}

// Per-sample: conditional RQS-inverse on odd dims using p, reinterleave z.
__global__ __launch_bounds__(256) void post_k(
  const float* __restrict__ zid, const float* __restrict__ ztr,
  const float* __restrict__ p, float* __restrict__ z, float* __restrict__ logdet)
{
  int n = blockIdx.x*256 + threadIdx.x;
  if (n >= N_SAMP) return;
  float ld = 0.f;
  #pragma unroll
  for (int k=0;k<DTR;k++){
    const float* pr = p + n*PDIM + k*(3*KB-1);
    float uwv[KB], uhv[KB], udv[KB-1];
    #pragma unroll
    for (int b=0;b<KB;b++){ uwv[b]=pr[b]*0.0625f; uhv[b]=pr[KB+b]*0.0625f; }
    #pragma unroll
    for (int b=0;b<KB-1;b++) udv[b]=pr[2*KB+b];
    float o, nl;
    rqs_inv1(ztr[n*DTR+k], uwv, uhv, udv, &o, &nl);
    z[n*LAT + 2*k]   = zid[n*DTR+k];
    z[n*LAT + 2*k+1] = o;
    ld += nl;
  }
  logdet[n] += ld;
}

// Per-sample Gaussian base log-prob + final NLL.
__global__ __launch_bounds__(256) void final_k(
  const float* __restrict__ ctx, const float* __restrict__ q0W,
  const float* __restrict__ q0b, const float* __restrict__ z,
  const float* __restrict__ logdet, float* __restrict__ out)
{
  int n = blockIdx.x*256 + threadIdx.x;
  if (n >= N_SAMP) return;
  float acc[2*LAT];
  #pragma unroll
  for (int m=0;m<2*LAT;m++) acc[m] = q0b[m];
  for (int k=0;k<CTXD;k++){
    float cv = ctx[n*CTXD + k];
    #pragma unroll
    for (int m=0;m<2*LAT;m++) acc[m] = fmaf(cv, q0W[k*2*LAT + m], acc[m]);
  }
  float s = 0.f;
  #pragma unroll
  for (int dd=0;dd<LAT;dd++){
    float ls = acc[LAT+dd];
    float t = (z[n*LAT+dd] - acc[dd]) * expf(-ls);
    s += ls + 0.5f*t*t;
  }
  float logp = -14.703016531f - s;   // -0.5*16*log(2*pi)
  out[n] = -(logp + logdet[n]);
}

extern "C" void kernel_launch(void* const* d_in, const int* in_sizes, int n_in,
                              void* d_out, int out_size, void* d_ws, size_t ws_size,
                              hipStream_t stream)
{
  const float* x      = (const float*)d_in[0];
  const float* params = (const float*)d_in[1];
  const float* W_in   = (const float*)d_in[2];
  const float* b_in   = (const float*)d_in[3];
  const float* W1     = (const float*)d_in[4];
  const float* b1     = (const float*)d_in[5];
  const float* W2     = (const float*)d_in[6];
  const float* b2     = (const float*)d_in[7];
  const float* Wc     = (const float*)d_in[8];
  const float* bc     = (const float*)d_in[9];
  const float* Wf     = (const float*)d_in[10];
  const float* bf     = (const float*)d_in[11];
  const float* un_w   = (const float*)d_in[12];
  const float* un_h   = (const float*)d_in[13];
  const float* un_d   = (const float*)d_in[14];
  const float* lu_lo  = (const float*)d_in[15];
  const float* lu_up  = (const float*)d_in[16];
  const float* lu_ud  = (const float*)d_in[17];
  const float* lu_b   = (const float*)d_in[18];
  const float* q0W    = (const float*)d_in[19];
  const float* q0b    = (const float*)d_in[20];
  const int*   perms  = (const int*)d_in[21];
  float* out = (float*)d_out;

  // workspace layout (floats); total ~17.9 MB
  float* ws     = (float*)d_ws;
  float* z      = ws;                      // N*16
  float* logdet = z   + N_SAMP*LAT;        // N
  float* zid    = logdet + N_SAMP;         // N*8
  float* ztr    = zid + N_SAMP*DID;        // N*8
  float* h      = ztr + N_SAMP*DID;        // N*256
  float* t1     = h   + N_SAMP*HIDD;       // N*256
  float* p      = t1;                      // overlay: t1 dead when p is written

  init_k<<<dim3((N_SAMP*LAT+255)/256), 256, 0, stream>>>(x, z, logdet);

  for (int i = NBLK-1; i >= 0; --i) {
    pre_k<<<dim3(N_SAMP/256), 256, 0, stream>>>(
        z, zid, ztr, logdet,
        lu_lo + i*120, lu_up + i*120, lu_ud + i*LAT, lu_b + i*LAT,
        un_w + i*DID*KB, un_h + i*DID*KB, un_d + i*DID*(KB-1), perms + i*LAT);

    // h = concat(zid, ctx) @ W_in + b_in   [K=264, M=256]
    gemm_k<2,0><<<dim3(4,128), 256, 0, stream>>>(
        zid, DID, params, W_in + i*(DID+CTXD)*HIDD, b_in + i*HIDD,
        nullptr, nullptr, h, HIDD, DID+CTXD, HIDD);

    for (int j=0;j<NRES;j++){
      const float* w1p = W1 + (size_t)(i*NRES+j)*HIDD*HIDD;
      const float* b1p = b1 + (i*NRES+j)*HIDD;
      const float* w2p = W2 + (size_t)(i*NRES+j)*HIDD*HIDD;
      const float* b2p = b2 + (i*NRES+j)*HIDD;
      const float* wcp = Wc + (size_t)(i*NRES+j)*CTXD*HIDD;
      const float* bcp = bc + (i*NRES+j)*HIDD;

      // t1 = relu(h) @ W1 + b1
      gemm_k<1,0><<<dim3(4,128), 256, 0, stream>>>(
          h, HIDD, nullptr, w1p, b1p, nullptr, nullptr, t1, HIDD, HIDD, HIDD);
      // h += (relu(t1) @ W2 + b2) * sigmoid(ctx @ Wc + bc)
      gemm_k<1,1><<<dim3(4,128), 256, 0, stream>>>(
          t1, HIDD, params, w2p, b2p, wcp, bcp, h, HIDD, HIDD, HIDD);
    }

    // p = h @ Wf + bf   [K=256, M=184]
    gemm_k<0,0><<<dim3(3,128), 256, 0, stream>>>(
        h, HIDD, nullptr, Wf + (size_t)i*HIDD*PDIM, bf + i*PDIM,
        nullptr, nullptr, p, PDIM, HIDD, PDIM);

    post_k<<<dim3(N_SAMP/256), 256, 0, stream>>>(zid, ztr, p, z, logdet);
  }

  final_k<<<dim3(N_SAMP/256), 256, 0, stream>>>(params, q0W, q0b, z, logdet, out);
}

// Round 2
// 557.500 us; speedup vs baseline: 11.2280x; 11.2280x over previous
//
#include <hip/hip_runtime.h>
#include <math.h>

#define N_SAMP 8192
#define LAT 16
#define DID 8
#define DTR 8
#define KB 8
#define CTXD 256
#define HIDD 256
#define NRES 2
#define NBLK 8
#define PDIM 184
#define TAILF 3.0f
#define RB 32

typedef unsigned short ushort_t;
typedef short short8v __attribute__((ext_vector_type(8)));
typedef float f32x4 __attribute__((ext_vector_type(4)));

// packed-weight sizes (elements)
#define WIN_PACK   73728   // 9 ksteps * 16 nblk * 512
#define WSQ_PACK   65536   // 8 * 16 * 512
#define WF_PACK    49152   // 8 * 12 * 512
#define BLK_PACK   516096  // WIN + 6*WSQ + WF
#define OFF_WSQ    9216    // in short8 units: 73728/8
#define OFF_WF     58368   // (73728+6*65536)/8

__device__ __forceinline__ ushort_t f2bf(float f){
  unsigned u = __builtin_bit_cast(unsigned, f);
  unsigned r = (u + 0x7fffu + ((u>>16)&1u)) >> 16;
  return (ushort_t)r;
}
__device__ __forceinline__ float softplusf(float x){
  return (x > 20.0f) ? x : log1pf(expf(x));
}
__device__ __forceinline__ f32x4 MFMA(short8v a, short8v b, f32x4 c){
  return __builtin_amdgcn_mfma_f32_16x16x32_bf16(a, b, c, 0, 0, 0);
}
// swizzled LDS bf16 tile helpers ([RB][256] ushort, 512B rows)
__device__ __forceinline__ short8v ldA(const void* tile, int row, int k){
  int byte = (row*512 + k*2) ^ ((row&7)<<4);
  return *(const short8v*)((const char*)tile + byte);
}
__device__ __forceinline__ void stBF(void* tile, int row, int col, float v){
  int byte = (row*512 + col*2) ^ ((row&7)<<4);
  *(ushort_t*)((char*)tile + byte) = f2bf(v);
}

// register-version inverse RQS (verified round-1)
__device__ __forceinline__ void rqs_inv1(float x, const float* uw, const float* uh,
                                         const float* ud, float* outp, float* nladp)
{
  const float T = TAILF;
  bool inside = (x >= -T) && (x <= T);
  float cw[KB+1], wv[KB], ch[KB+1], hv[KB], dv[KB+1];
  {
    float m = uw[0];
    #pragma unroll
    for (int k=1;k<KB;k++) m = fmaxf(m, uw[k]);
    float e[KB]; float ssum = 0.f;
    #pragma unroll
    for (int k=0;k<KB;k++){ e[k] = expf(uw[k]-m); ssum += e[k]; }
    float inv = 1.f/ssum; float c = 0.f;
    cw[0] = -T;
    #pragma unroll
    for (int k=0;k<KB;k++){ c += 0.001f + (1.f-0.001f*KB)*e[k]*inv; cw[k+1] = 2.f*T*c - T; }
    cw[KB] = T;
    #pragma unroll
    for (int k=0;k<KB;k++) wv[k] = cw[k+1]-cw[k];
  }
  {
    float m = uh[0];
    #pragma unroll
    for (int k=1;k<KB;k++) m = fmaxf(m, uh[k]);
    float e[KB]; float ssum = 0.f;
    #pragma unroll
    for (int k=0;k<KB;k++){ e[k] = expf(uh[k]-m); ssum += e[k]; }
    float inv = 1.f/ssum; float c = 0.f;
    ch[0] = -T;
    #pragma unroll
    for (int k=0;k<KB;k++){ c += 0.001f + (1.f-0.001f*KB)*e[k]*inv; ch[k+1] = 2.f*T*c - T; }
    ch[KB] = T;
    #pragma unroll
    for (int k=0;k<KB;k++) hv[k] = ch[k+1]-ch[k];
  }
  dv[0] = 1.f; dv[KB] = 1.f;
  #pragma unroll
  for (int k=0;k<KB-1;k++) dv[k+1] = 0.001f + softplusf(ud[k]);

  float xc = fminf(fmaxf(x, -T), T);
  int idx = 0;
  #pragma unroll
  for (int k=1;k<KB;k++) idx += (xc >= ch[k]) ? 1 : 0;

  float icw=cw[0], iw=wv[0], ich=ch[0], ih=hv[0], d0=dv[0], d1=dv[1];
  #pragma unroll
  for (int k=1;k<KB;k++){
    bool sel = (idx==k);
    icw = sel?cw[k]:icw; iw = sel?wv[k]:iw; ich = sel?ch[k]:ich;
    ih = sel?hv[k]:ih; d0 = sel?dv[k]:d0; d1 = sel?dv[k+1]:d1;
  }
  float delta = ih/iw;
  float sq = d0 + d1 - 2.f*delta;
  float yv = xc - ich;
  float aa = yv*sq + ih*(delta-d0);
  float bb = ih*d0 - yv*sq;
  float cc = -delta*yv;
  float disc = fmaxf(bb*bb - 4.f*aa*cc, 0.f);
  float root = 2.f*cc / (-bb - sqrtf(disc));
  float o = root*iw + icw;
  float t1m = root*(1.f-root);
  float den = delta + sq*t1m;
  float num = delta*delta*(d1*root*root + 2.f*delta*t1m + d0*(1.f-root)*(1.f-root));
  float lad = logf(num) - 2.f*logf(den);
  *outp = inside ? o : x;
  *nladp = inside ? -lad : 0.f;
}

// LDS-knot apply (uncond spline: knots shared across rows)
__device__ __forceinline__ void rqs_apply_lds(float x, const float* cw, const float* ch,
                                              const float* dv, float* outp, float* nladp)
{
  const float T = TAILF;
  bool inside = (x >= -T) && (x <= T);
  float xc = fminf(fmaxf(x, -T), T);
  int idx = 0;
  #pragma unroll
  for (int k=1;k<KB;k++) idx += (xc >= ch[k]) ? 1 : 0;
  float icw = cw[idx], iw = cw[idx+1]-icw;
  float ich = ch[idx], ih = ch[idx+1]-ich;
  float d0 = dv[idx], d1 = dv[idx+1];
  float delta = ih/iw;
  float sq = d0 + d1 - 2.f*delta;
  float yv = xc - ich;
  float aa = yv*sq + ih*(delta-d0);
  float bb = ih*d0 - yv*sq;
  float cc = -delta*yv;
  float disc = fmaxf(bb*bb - 4.f*aa*cc, 0.f);
  float root = 2.f*cc / (-bb - sqrtf(disc));
  float o = root*iw + icw;
  float t1m = root*(1.f-root);
  float den = delta + sq*t1m;
  float num = delta*delta*(d1*root*root + 2.f*delta*t1m + d0*(1.f-root)*(1.f-root));
  float lad = logf(num) - 2.f*logf(den);
  *outp = inside ? o : x;
  *nladp = inside ? -lad : 0.f;
}

__global__ __launch_bounds__(256) void init_k(const float* __restrict__ x,
                                              float* __restrict__ z, float* __restrict__ logdet)
{
  int i = blockIdx.x*256 + threadIdx.x;
  if (i < N_SAMP*LAT) z[i] = x[i];
  if (i < N_SAMP) logdet[i] = 0.f;
}

// pack all weights into B-fragment-linear bf16 layout
__global__ __launch_bounds__(256) void pack_w_k(
  const float* __restrict__ W_in, const float* __restrict__ W1, const float* __restrict__ W2,
  const float* __restrict__ Wc, const float* __restrict__ Wf, ushort_t* __restrict__ wp)
{
  int t = blockIdx.x*256 + threadIdx.x;
  if (t >= 8*64512) return;
  int blk = t / 64512;
  int r = t % 64512;
  ushort_t* dst = wp + (size_t)blk*BLK_PACK;
  float vals[8];
  if (r < 9216){                      // W_in: 9 ksteps, zid(8)+pad(24)+ctx(256)
    int kt = r/1024, n = (r/64)%16, lane = r%64;
    const float* w = W_in + (size_t)blk*264*256;
    int col = n*16 + (lane&15);
    #pragma unroll
    for (int j=0;j<8;j++){
      int k = kt*32 + (lane>>4)*8 + j;
      vals[j] = (k < 32) ? ((k < 8) ? w[k*256+col] : 0.f) : w[(k-24)*256+col];
    }
    dst += ((size_t)(kt*16+n)*64 + lane)*8;
  } else if ((r -= 9216) < 49152){    // W1/W2/Wc for j=0,1
    int m = r/8192, rr = r%8192;
    int kt = rr/1024, n = (rr/64)%16, lane = rr%64;
    int j2 = m/3, which = m%3;
    const float* w = (which==0 ? W1 : which==1 ? W2 : Wc) + (size_t)(blk*2+j2)*256*256;
    int col = n*16 + (lane&15);
    #pragma unroll
    for (int j=0;j<8;j++){
      int k = kt*32 + (lane>>4)*8 + j;
      vals[j] = w[k*256+col];
    }
    dst += WIN_PACK + (size_t)m*WSQ_PACK + ((size_t)(kt*16+n)*64+lane)*8;
  } else {                            // Wf: 12 col-blocks (184 padded to 192)
    r -= 49152;
    int kt = r/768, n = (r/64)%12, lane = r%64;
    const float* w = Wf + (size_t)blk*256*184;
    int col = n*16 + (lane&15);
    #pragma unroll
    for (int j=0;j<8;j++){
      int k = kt*32 + (lane>>4)*8 + j;
      vals[j] = (col < 184) ? w[k*184+col] : 0.f;
    }
    dst += (size_t)OFF_WF*8 + ((size_t)(kt*12+n)*64+lane)*8;
  }
  #pragma unroll
  for (int j=0;j<8;j++) dst[j] = f2bf(vals[j]);
}

__global__ __launch_bounds__(256) void pack_ctx_k(const float* __restrict__ p, ushort_t* __restrict__ c)
{
  int t = blockIdx.x*256 + threadIdx.x;     // 262144 threads, 8 elems each
  int base = t*8;
  #pragma unroll
  for (int j=0;j<8;j++) c[base+j] = f2bf(p[base+j]);
}

// ---- one fused kernel per flow block: pre + cond_net (MFMA) + post ----
__global__ __launch_bounds__(256,1) void block_k(
  float* __restrict__ zg, float* __restrict__ logdet_g,
  const ushort_t* __restrict__ ctxp, const ushort_t* __restrict__ wpack,
  const float* __restrict__ b_in, const float* __restrict__ b1, const float* __restrict__ b2,
  const float* __restrict__ bc, const float* __restrict__ bf_,
  const float* __restrict__ un_w, const float* __restrict__ un_h, const float* __restrict__ un_d,
  const float* __restrict__ lu_lo, const float* __restrict__ lu_up,
  const float* __restrict__ lu_ud, const float* __restrict__ lu_b,
  const int* __restrict__ perms, int blk)
{
  __shared__ float   s_zw[RB][16];     // raw z, later w (LU output)
  __shared__ float   s_y[RB][16];
  __shared__ float   s_zid[RB][8], s_ztr[RB][8];
  __shared__ float   s_ld[RB];
  __shared__ ushort_t s_actx[RB][256]; // swizzled ctx bf16
  __shared__ ushort_t s_azid[RB][32];  // kstep-0 A tile (zid | zeros), linear
  __shared__ ushort_t s_hr[RB][256];   // relu(h) (or plain h after last res) bf16, swizzled
  __shared__ ushort_t s_tb[RB][256];   // relu(t1) bf16, swizzled
  __shared__ float   s_pb[RB][196];    // spline params p, f32
  __shared__ float   s_ucw[8][9], s_uch[8][9], s_ud[8][9];
  __shared__ float   s_dg[16], s_slog[16], s_ldc;
  __shared__ int     s_perm[16];

  const int tid = threadIdx.x;
  const int r0 = blockIdx.x * RB;
  const int wid = tid >> 6, lane = tid & 63;
  const int rA = lane & 15, kA8 = (lane>>4)*8;

  const float* lu_up_g = lu_up + blk*120;
  const float* lu_lo_g = lu_lo + blk*120;
  const float* lu_ud_g = lu_ud + blk*16;
  const float* lu_b_g  = lu_b  + blk*16;
  const short8v* Wpk8  = (const short8v*)(wpack + (size_t)blk*BLK_PACK);

  // ---- P0: stage z, ctx, logdet, perm, diag
  for (int i = tid; i < RB*16; i += 256)
    s_zw[i>>4][i&15] = zg[(r0 + (i>>4))*16 + (i&15)];
  for (int i = tid; i < RB*32; i += 256){
    int row = i >> 5, c8 = i & 31;
    short8v v = *(const short8v*)(ctxp + (size_t)(r0+row)*256 + c8*8);
    int byte = (row*512 + c8*16) ^ ((row&7)<<4);
    *(short8v*)((char*)s_actx + byte) = v;
  }
  if (tid < RB) s_ld[tid] = logdet_g[r0 + tid];
  if (tid < 16){
    s_perm[tid] = perms[blk*16 + tid];
    float dg = softplusf(lu_ud_g[tid]) + 0.001f;
    s_dg[tid] = dg; s_slog[tid] = logf(dg);
  }
  __syncthreads();

  // ---- P1: LU upper (permuted input)
  for (int u = tid; u < RB*16; u += 256){
    int row = u >> 4, c = u & 15;
    float acc = s_dg[c] * s_zw[row][s_perm[c]];
    for (int cc = c+1; cc < 16; cc++){
      int t = c*15 - (c*(c-1))/2 + (cc-c-1);
      acc += lu_up_g[t] * s_zw[row][s_perm[cc]];
    }
    s_y[row][c] = acc;
  }
  __syncthreads();

  // ---- P2: LU lower + bias (overwrite s_zw with w)
  for (int u = tid; u < RB*16; u += 256){
    int row = u >> 4, c = u & 15;
    float acc = s_y[row][c] + lu_b_g[c];
    for (int cc = 0; cc < c; cc++)
      acc += lu_lo_g[(c*(c-1))/2 + cc] * s_y[row][cc];
    s_zw[row][c] = acc;
  }
  __syncthreads();

  // ---- P3: uncond knots + logdet const
  if (tid < 8){
    const float* uwp = un_w + blk*64 + tid*8;
    const float* uhp = un_h + blk*64 + tid*8;
    const float* udp = un_d + blk*56 + tid*7;
    float m = uwp[0];
    #pragma unroll
    for (int k=1;k<8;k++) m = fmaxf(m, uwp[k]);
    float e[8], s=0.f;
    #pragma unroll
    for (int k=0;k<8;k++){ e[k]=expf(uwp[k]-m); s+=e[k]; }
    float inv=1.f/s, c=0.f;
    s_ucw[tid][0] = -TAILF;
    #pragma unroll
    for (int k=0;k<8;k++){ c += 0.001f + (1.f-0.008f)*e[k]*inv; s_ucw[tid][k+1] = 2.f*TAILF*c - TAILF; }
    s_ucw[tid][8] = TAILF;
    m = uhp[0];
    #pragma unroll
    for (int k=1;k<8;k++) m = fmaxf(m, uhp[k]);
    s=0.f;
    #pragma unroll
    for (int k=0;k<8;k++){ e[k]=expf(uhp[k]-m); s+=e[k]; }
    inv=1.f/s; c=0.f;
    s_uch[tid][0] = -TAILF;
    #pragma unroll
    for (int k=0;k<8;k++){ c += 0.001f + (1.f-0.008f)*e[k]*inv; s_uch[tid][k+1] = 2.f*TAILF*c - TAILF; }
    s_uch[tid][8] = TAILF;
    s_ud[tid][0] = 1.f; s_ud[tid][8] = 1.f;
    #pragma unroll
    for (int k=0;k<7;k++) s_ud[tid][k+1] = 0.001f + softplusf(udp[k]);
  }
  if (tid == 8){
    float s = 0.f;
    #pragma unroll
    for (int c=0;c<16;c++) s += s_slog[c];
    s_ldc = s;
  }
  __syncthreads();

  // ---- P4: uncond spline on even dims
  {
    int row = tid >> 3, k = tid & 7;
    float o, nl;
    rqs_apply_lds(s_zw[row][2*k], s_ucw[k], s_uch[k], s_ud[k], &o, &nl);
    s_zid[row][k] = o;
    s_ztr[row][k] = s_zw[row][2*k+1];
    s_azid[row][k] = f2bf(o);
    s_azid[row][k+8] = 0; s_azid[row][k+16] = 0; s_azid[row][k+24] = 0;
    float t = nl;
    t += __shfl_xor(t,1); t += __shfl_xor(t,2); t += __shfl_xor(t,4);
    if (k == 0) s_ld[row] += s_ldc + t;
  }
  __syncthreads();

  float hreg[2][4][4];   // persistent h (f32) for this wave's 2x4 fragments

  // ---- P5: GEMM1  h = [zid|ctx] @ W_in + b_in   (9 ksteps)
  {
    f32x4 acc[2][4];
    #pragma unroll
    for (int f=0;f<2;f++)
      #pragma unroll
      for (int n=0;n<4;n++) acc[f][n] = (f32x4){0,0,0,0};
    const short8v* Wp = Wpk8;  // W_in pack at offset 0
    short8v a0 = *(const short8v*)((const char*)s_azid + rA*64 + kA8*2);
    short8v a1 = *(const short8v*)((const char*)s_azid + (rA+16)*64 + kA8*2);
    short8v b0[4], bn[4], an0=a0, an1=a1;
    #pragma unroll
    for (int n=0;n<4;n++) b0[n] = Wp[(size_t)(0*16 + 4*wid+n)*64 + lane];
    for (int kt=0; kt<9; ++kt){
      if (kt < 8){
        an0 = ldA(s_actx, rA,    kt*32 + kA8);
        an1 = ldA(s_actx, rA+16, kt*32 + kA8);
        #pragma unroll
        for (int n=0;n<4;n++) bn[n] = Wp[(size_t)((kt+1)*16 + 4*wid+n)*64 + lane];
      }
      #pragma unroll
      for (int n=0;n<4;n++){
        acc[0][n] = MFMA(a0, b0[n], acc[0][n]);
        acc[1][n] = MFMA(a1, b0[n], acc[1][n]);
      }
      a0=an0; a1=an1;
      #pragma unroll
      for (int n=0;n<4;n++) b0[n]=bn[n];
    }
    #pragma unroll
    for (int n=0;n<4;n++){
      int col = (4*wid+n)*16 + rA;
      float bv = b_in[blk*256 + col];
      #pragma unroll
      for (int f=0;f<2;f++)
        #pragma unroll
        for (int r=0;r<4;r++){
          int row = f*16 + (lane>>4)*4 + r;
          float h = acc[f][n][r] + bv;
          hreg[f][n][r] = h;
          stBF(s_hr, row, col, fmaxf(h, 0.f));
        }
    }
  }
  __syncthreads();

  // ---- P6: residual blocks
  #pragma unroll
  for (int j=0;j<NRES;j++){
    // stage 1: t = relu( relu(h) @ W1 + b1 )
    {
      f32x4 acc[2][4];
      #pragma unroll
      for (int f=0;f<2;f++)
        #pragma unroll
        for (int n=0;n<4;n++) acc[f][n] = (f32x4){0,0,0,0};
      const short8v* Wp = Wpk8 + OFF_WSQ + (size_t)(j*3+0)*8192;
      short8v a0 = ldA(s_hr, rA, kA8), a1 = ldA(s_hr, rA+16, kA8);
      short8v b0[4], bn[4], an0=a0, an1=a1;
      #pragma unroll
      for (int n=0;n<4;n++) b0[n] = Wp[(size_t)(4*wid+n)*64 + lane];
      for (int kt=0; kt<8; ++kt){
        if (kt < 7){
          an0 = ldA(s_hr, rA,    (kt+1)*32 + kA8);
          an1 = ldA(s_hr, rA+16, (kt+1)*32 + kA8);
          #pragma unroll
          for (int n=0;n<4;n++) bn[n] = Wp[(size_t)((kt+1)*16 + 4*wid+n)*64 + lane];
        }
        #pragma unroll
        for (int n=0;n<4;n++){
          acc[0][n] = MFMA(a0, b0[n], acc[0][n]);
          acc[1][n] = MFMA(a1, b0[n], acc[1][n]);
        }
        a0=an0; a1=an1;
        #pragma unroll
        for (int n=0;n<4;n++) b0[n]=bn[n];
      }
      #pragma unroll
      for (int n=0;n<4;n++){
        int col = (4*wid+n)*16 + rA;
        float bv = b1[(blk*2+j)*256 + col];
        #pragma unroll
        for (int f=0;f<2;f++)
          #pragma unroll
          for (int r=0;r<4;r++){
            int row = f*16 + (lane>>4)*4 + r;
            stBF(s_tb, row, col, fmaxf(acc[f][n][r] + bv, 0.f));
          }
      }
    }
    __syncthreads();
    // stage 2: h += (t @ W2 + b2) * sigmoid(ctx @ Wc + bc)
    {
      f32x4 acc[2][4], accg[2][4];
      #pragma unroll
      for (int f=0;f<2;f++)
        #pragma unroll
        for (int n=0;n<4;n++){ acc[f][n] = (f32x4){0,0,0,0}; accg[f][n] = (f32x4){0,0,0,0}; }
      const short8v* Wv = Wpk8 + OFF_WSQ + (size_t)(j*3+1)*8192;
      const short8v* Wg = Wpk8 + OFF_WSQ + (size_t)(j*3+2)*8192;
      short8v at0 = ldA(s_tb, rA, kA8),  at1 = ldA(s_tb, rA+16, kA8);
      short8v ac0 = ldA(s_actx, rA, kA8), ac1 = ldA(s_actx, rA+16, kA8);
      short8v bv0[4], bg0[4], bvn[4], bgn[4];
      short8v atn0=at0, atn1=at1, acn0=ac0, acn1=ac1;
      #pragma unroll
      for (int n=0;n<4;n++){
        bv0[n] = Wv[(size_t)(4*wid+n)*64 + lane];
        bg0[n] = Wg[(size_t)(4*wid+n)*64 + lane];
      }
      for (int kt=0; kt<8; ++kt){
        if (kt < 7){
          atn0 = ldA(s_tb, rA,    (kt+1)*32 + kA8);
          atn1 = ldA(s_tb, rA+16, (kt+1)*32 + kA8);
          acn0 = ldA(s_actx, rA,    (kt+1)*32 + kA8);
          acn1 = ldA(s_actx, rA+16, (kt+1)*32 + kA8);
          #pragma unroll
          for (int n=0;n<4;n++){
            bvn[n] = Wv[(size_t)((kt+1)*16 + 4*wid+n)*64 + lane];
            bgn[n] = Wg[(size_t)((kt+1)*16 + 4*wid+n)*64 + lane];
          }
        }
        #pragma unroll
        for (int n=0;n<4;n++){
          acc[0][n]  = MFMA(at0, bv0[n], acc[0][n]);
          acc[1][n]  = MFMA(at1, bv0[n], acc[1][n]);
          accg[0][n] = MFMA(ac0, bg0[n], accg[0][n]);
          accg[1][n] = MFMA(ac1, bg0[n], accg[1][n]);
        }
        at0=atn0; at1=atn1; ac0=acn0; ac1=acn1;
        #pragma unroll
        for (int n=0;n<4;n++){ bv0[n]=bvn[n]; bg0[n]=bgn[n]; }
      }
      bool last = (j == NRES-1);
      #pragma unroll
      for (int n=0;n<4;n++){
        int col = (4*wid+n)*16 + rA;
        float b2v = b2[(blk*2+j)*256 + col];
        float bcv = bc[(blk*2+j)*256 + col];
        #pragma unroll
        for (int f=0;f<2;f++)
          #pragma unroll
          for (int r=0;r<4;r++){
            int row = f*16 + (lane>>4)*4 + r;
            float v = acc[f][n][r] + b2v;
            float g = accg[f][n][r] + bcv;
            float sg = 1.f/(1.f + expf(-g));
            float h = hreg[f][n][r] + v*sg;
            hreg[f][n][r] = h;
            stBF(s_hr, row, col, last ? h : fmaxf(h, 0.f));  // GEMM5 consumes PLAIN h
          }
      }
    }
    __syncthreads();
  }

  // ---- P7: GEMM5  p = h @ Wf + bf  (184 cols, padded 192; 3 col-blocks/wave)
  {
    f32x4 acc[2][3];
    #pragma unroll
    for (int f=0;f<2;f++)
      #pragma unroll
      for (int n=0;n<3;n++) acc[f][n] = (f32x4){0,0,0,0};
    const short8v* Wp = Wpk8 + OFF_WF;
    short8v a0 = ldA(s_hr, rA, kA8), a1 = ldA(s_hr, rA+16, kA8);
    short8v b0[3], bn[3], an0=a0, an1=a1;
    #pragma unroll
    for (int n=0;n<3;n++) b0[n] = Wp[(size_t)(3*wid+n)*64 + lane];
    for (int kt=0; kt<8; ++kt){
      if (kt < 7){
        an0 = ldA(s_hr, rA,    (kt+1)*32 + kA8);
        an1 = ldA(s_hr, rA+16, (kt+1)*32 + kA8);
        #pragma unroll
        for (int n=0;n<3;n++) bn[n] = Wp[(size_t)((kt+1)*12 + 3*wid+n)*64 + lane];
      }
      #pragma unroll
      for (int n=0;n<3;n++){
        acc[0][n] = MFMA(a0, b0[n], acc[0][n]);
        acc[1][n] = MFMA(a1, b0[n], acc[1][n]);
      }
      a0=an0; a1=an1;
      #pragma unroll
      for (int n=0;n<3;n++) b0[n]=bn[n];
    }
    #pragma unroll
    for (int n=0;n<3;n++){
      int col = (3*wid+n)*16 + rA;
      if (col < PDIM){
        float bv = bf_[blk*PDIM + col];
        #pragma unroll
        for (int f=0;f<2;f++)
          #pragma unroll
          for (int r=0;r<4;r++){
            int row = f*16 + (lane>>4)*4 + r;
            s_pb[row][col] = acc[f][n][r] + bv;
          }
      }
    }
  }
  __syncthreads();

  // ---- P8: conditional spline on odd dims + writeback
  {
    int row = tid >> 3, k = tid & 7;
    float pr[23];
    #pragma unroll
    for (int jj=0;jj<23;jj++) pr[jj] = s_pb[row][k*23 + jj];
    float uw[8], uh[8], ud[7];
    #pragma unroll
    for (int b=0;b<8;b++){ uw[b] = pr[b]*0.0625f; uh[b] = pr[8+b]*0.0625f; }
    #pragma unroll
    for (int b=0;b<7;b++) ud[b] = pr[16+b];
    float o, nl;
    rqs_inv1(s_ztr[row][k], uw, uh, ud, &o, &nl);
    zg[(r0+row)*16 + 2*k]   = s_zid[row][k];
    zg[(r0+row)*16 + 2*k+1] = o;
    float t = nl;
    t += __shfl_xor(t,1); t += __shfl_xor(t,2); t += __shfl_xor(t,4);
    if (k == 0) logdet_g[r0+row] = s_ld[row] + t;
  }
}

__global__ __launch_bounds__(64) void final_k(
  const float* __restrict__ ctx, const float* __restrict__ q0W,
  const float* __restrict__ q0b, const float* __restrict__ z,
  const float* __restrict__ logdet, float* __restrict__ out)
{
  int n = blockIdx.x*64 + threadIdx.x;
  if (n >= N_SAMP) return;
  float acc[2*LAT];
  #pragma unroll
  for (int m=0;m<2*LAT;m++) acc[m] = q0b[m];
  for (int k=0;k<CTXD;k+=4){
    float4 cv = *(const float4*)&ctx[n*CTXD + k];
    #pragma unroll
    for (int m=0;m<2*LAT;m++){
      acc[m] = fmaf(cv.x, q0W[(k+0)*2*LAT + m], acc[m]);
      acc[m] = fmaf(cv.y, q0W[(k+1)*2*LAT + m], acc[m]);
      acc[m] = fmaf(cv.z, q0W[(k+2)*2*LAT + m], acc[m]);
      acc[m] = fmaf(cv.w, q0W[(k+3)*2*LAT + m], acc[m]);
    }
  }
  float s = 0.f;
  #pragma unroll
  for (int dd=0;dd<LAT;dd++){
    float ls = acc[LAT+dd];
    float t = (z[n*LAT+dd] - acc[dd]) * expf(-ls);
    s += ls + 0.5f*t*t;
  }
  float logp = -14.703016531f - s;
  out[n] = -(logp + logdet[n]);
}

extern "C" void kernel_launch(void* const* d_in, const int* in_sizes, int n_in,
                              void* d_out, int out_size, void* d_ws, size_t ws_size,
                              hipStream_t stream)
{
  const float* x      = (const float*)d_in[0];
  const float* params = (const float*)d_in[1];
  const float* W_in   = (const float*)d_in[2];
  const float* b_in   = (const float*)d_in[3];
  const float* W1     = (const float*)d_in[4];
  const float* b1     = (const float*)d_in[5];
  const float* W2     = (const float*)d_in[6];
  const float* b2     = (const float*)d_in[7];
  const float* Wc     = (const float*)d_in[8];
  const float* bc     = (const float*)d_in[9];
  const float* Wf     = (const float*)d_in[10];
  const float* bf_    = (const float*)d_in[11];
  const float* un_w   = (const float*)d_in[12];
  const float* un_h   = (const float*)d_in[13];
  const float* un_d   = (const float*)d_in[14];
  const float* lu_lo  = (const float*)d_in[15];
  const float* lu_up  = (const float*)d_in[16];
  const float* lu_ud  = (const float*)d_in[17];
  const float* lu_b   = (const float*)d_in[18];
  const float* q0W    = (const float*)d_in[19];
  const float* q0b    = (const float*)d_in[20];
  const int*   perms  = (const int*)d_in[21];
  float* out = (float*)d_out;

  // workspace layout
  float* ws      = (float*)d_ws;
  float* z       = ws;                        // 131072 f
  float* logdet  = z + N_SAMP*LAT;            // 8192 f
  ushort_t* ctxp = (ushort_t*)(logdet + N_SAMP);          // 2097152 us
  ushort_t* wpk  = ctxp + (size_t)N_SAMP*CTXD;            // 4128768 us

  pack_w_k<<<dim3(2016), 256, 0, stream>>>(W_in, W1, W2, Wc, Wf, wpk);
  pack_ctx_k<<<dim3(1024), 256, 0, stream>>>(params, ctxp);
  init_k<<<dim3(512), 256, 0, stream>>>(x, z, logdet);

  for (int i = NBLK-1; i >= 0; --i){
    block_k<<<dim3(N_SAMP/RB), 256, 0, stream>>>(
        z, logdet, ctxp, wpk,
        b_in, b1, b2, bc, bf_,
        un_w, un_h, un_d, lu_lo, lu_up, lu_ud, lu_b, perms, i);
  }

  final_k<<<dim3(N_SAMP/64), 64, 0, stream>>>(params, q0W, q0b, z, logdet, out);
}

// Round 3
// 322.434 us; speedup vs baseline: 19.4136x; 1.7290x over previous
//
#include <hip/hip_runtime.h>
#include <math.h>

#define N_SAMP 8192
#define LAT 16
#define DID 8
#define DTR 8
#define KB 8
#define CTXD 256
#define HIDD 256
#define NRES 2
#define NBLK 8
#define PDIM 184
#define TAILF 3.0f
#define RB 32

typedef unsigned short ushort_t;
typedef short short8v __attribute__((ext_vector_type(8)));
typedef float f32x4 __attribute__((ext_vector_type(4)));

// packed-weight sizes (elements)
#define WIN_PACK   73728   // 9 ksteps * 16 nblk * 512
#define WSQ_PACK   65536   // 8 * 16 * 512
#define WF_PACK    49152   // 8 * 12 * 512
#define BLK_PACK   516096  // WIN + 6*WSQ + WF
#define OFF_WSQ    9216    // in short8 units
#define OFF_WF     58368

__device__ __forceinline__ ushort_t f2bf(float f){
  unsigned u = __builtin_bit_cast(unsigned, f);
  unsigned r = (u + 0x7fffu + ((u>>16)&1u)) >> 16;
  return (ushort_t)r;
}
__device__ __forceinline__ float softplusf(float x){
  return (x > 20.0f) ? x : log1pf(expf(x));
}
__device__ __forceinline__ f32x4 MFMA(short8v a, short8v b, f32x4 c){
  return __builtin_amdgcn_mfma_f32_16x16x32_bf16(a, b, c, 0, 0, 0);
}
// swizzled LDS bf16 tile helpers ([RB][256] ushort, 512B rows)
__device__ __forceinline__ short8v ldA(const void* tile, int row, int k){
  int byte = (row*512 + k*2) ^ ((row&7)<<4);
  return *(const short8v*)((const char*)tile + byte);
}
__device__ __forceinline__ void stBF(void* tile, int row, int col, float v){
  int byte = (row*512 + col*2) ^ ((row&7)<<4);
  *(ushort_t*)((char*)tile + byte) = f2bf(v);
}
__device__ __forceinline__ void st8(void* tile, int row, int col, short8v v){
  int byte = (row*512 + col*2) ^ ((row&7)<<4);
  *(short8v*)((char*)tile + byte) = v;
}

// register-version inverse RQS (verified)
__device__ __forceinline__ void rqs_inv1(float x, const float* uw, const float* uh,
                                         const float* ud, float* outp, float* nladp)
{
  const float T = TAILF;
  bool inside = (x >= -T) && (x <= T);
  float cw[KB+1], wv[KB], ch[KB+1], hv[KB], dv[KB+1];
  {
    float m = uw[0];
    #pragma unroll
    for (int k=1;k<KB;k++) m = fmaxf(m, uw[k]);
    float e[KB]; float ssum = 0.f;
    #pragma unroll
    for (int k=0;k<KB;k++){ e[k] = expf(uw[k]-m); ssum += e[k]; }
    float inv = 1.f/ssum; float c = 0.f;
    cw[0] = -T;
    #pragma unroll
    for (int k=0;k<KB;k++){ c += 0.001f + (1.f-0.008f)*e[k]*inv; cw[k+1] = 2.f*T*c - T; }
    cw[KB] = T;
    #pragma unroll
    for (int k=0;k<KB;k++) wv[k] = cw[k+1]-cw[k];
  }
  {
    float m = uh[0];
    #pragma unroll
    for (int k=1;k<KB;k++) m = fmaxf(m, uh[k]);
    float e[KB]; float ssum = 0.f;
    #pragma unroll
    for (int k=0;k<KB;k++){ e[k] = expf(uh[k]-m); ssum += e[k]; }
    float inv = 1.f/ssum; float c = 0.f;
    ch[0] = -T;
    #pragma unroll
    for (int k=0;k<KB;k++){ c += 0.001f + (1.f-0.008f)*e[k]*inv; ch[k+1] = 2.f*T*c - T; }
    ch[KB] = T;
    #pragma unroll
    for (int k=0;k<KB;k++) hv[k] = ch[k+1]-ch[k];
  }
  dv[0] = 1.f; dv[KB] = 1.f;
  #pragma unroll
  for (int k=0;k<KB-1;k++) dv[k+1] = 0.001f + softplusf(ud[k]);

  float xc = fminf(fmaxf(x, -T), T);
  int idx = 0;
  #pragma unroll
  for (int k=1;k<KB;k++) idx += (xc >= ch[k]) ? 1 : 0;

  float icw=cw[0], iw=wv[0], ich=ch[0], ih=hv[0], d0=dv[0], d1=dv[1];
  #pragma unroll
  for (int k=1;k<KB;k++){
    bool sel = (idx==k);
    icw = sel?cw[k]:icw; iw = sel?wv[k]:iw; ich = sel?ch[k]:ich;
    ih = sel?hv[k]:ih; d0 = sel?dv[k]:d0; d1 = sel?dv[k+1]:d1;
  }
  float delta = ih/iw;
  float sq = d0 + d1 - 2.f*delta;
  float yv = xc - ich;
  float aa = yv*sq + ih*(delta-d0);
  float bb = ih*d0 - yv*sq;
  float cc = -delta*yv;
  float disc = fmaxf(bb*bb - 4.f*aa*cc, 0.f);
  float root = 2.f*cc / (-bb - sqrtf(disc));
  float o = root*iw + icw;
  float t1m = root*(1.f-root);
  float den = delta + sq*t1m;
  float num = delta*delta*(d1*root*root + 2.f*delta*t1m + d0*(1.f-root)*(1.f-root));
  float lad = logf(num) - 2.f*logf(den);
  *outp = inside ? o : x;
  *nladp = inside ? -lad : 0.f;
}

// LDS-knot apply (uncond spline)
__device__ __forceinline__ void rqs_apply_lds(float x, const float* cw, const float* ch,
                                              const float* dv, float* outp, float* nladp)
{
  const float T = TAILF;
  bool inside = (x >= -T) && (x <= T);
  float xc = fminf(fmaxf(x, -T), T);
  int idx = 0;
  #pragma unroll
  for (int k=1;k<KB;k++) idx += (xc >= ch[k]) ? 1 : 0;
  float icw = cw[idx], iw = cw[idx+1]-icw;
  float ich = ch[idx], ih = ch[idx+1]-ich;
  float d0 = dv[idx], d1 = dv[idx+1];
  float delta = ih/iw;
  float sq = d0 + d1 - 2.f*delta;
  float yv = xc - ich;
  float aa = yv*sq + ih*(delta-d0);
  float bb = ih*d0 - yv*sq;
  float cc = -delta*yv;
  float disc = fmaxf(bb*bb - 4.f*aa*cc, 0.f);
  float root = 2.f*cc / (-bb - sqrtf(disc));
  float o = root*iw + icw;
  float t1m = root*(1.f-root);
  float den = delta + sq*t1m;
  float num = delta*delta*(d1*root*root + 2.f*delta*t1m + d0*(1.f-root)*(1.f-root));
  float lad = logf(num) - 2.f*logf(den);
  *outp = inside ? o : x;
  *nladp = inside ? -lad : 0.f;
}

// pack all weights into B-fragment-linear bf16 layout (unchanged, verified)
__global__ __launch_bounds__(256) void pack_w_k(
  const float* __restrict__ W_in, const float* __restrict__ W1, const float* __restrict__ W2,
  const float* __restrict__ Wc, const float* __restrict__ Wf, ushort_t* __restrict__ wp)
{
  int t = blockIdx.x*256 + threadIdx.x;
  if (t >= 8*64512) return;
  int blk = t / 64512;
  int r = t % 64512;
  ushort_t* dst = wp + (size_t)blk*BLK_PACK;
  float vals[8];
  if (r < 9216){
    int kt = r/1024, n = (r/64)%16, lane = r%64;
    const float* w = W_in + (size_t)blk*264*256;
    int col = n*16 + (lane&15);
    #pragma unroll
    for (int j=0;j<8;j++){
      int k = kt*32 + (lane>>4)*8 + j;
      vals[j] = (k < 32) ? ((k < 8) ? w[k*256+col] : 0.f) : w[(k-24)*256+col];
    }
    dst += ((size_t)(kt*16+n)*64 + lane)*8;
  } else if ((r -= 9216) < 49152){
    int m = r/8192, rr = r%8192;
    int kt = rr/1024, n = (rr/64)%16, lane = rr%64;
    int j2 = m/3, which = m%3;
    const float* w = (which==0 ? W1 : which==1 ? W2 : Wc) + (size_t)(blk*2+j2)*256*256;
    int col = n*16 + (lane&15);
    #pragma unroll
    for (int j=0;j<8;j++){
      int k = kt*32 + (lane>>4)*8 + j;
      vals[j] = w[k*256+col];
    }
    dst += WIN_PACK + (size_t)m*WSQ_PACK + ((size_t)(kt*16+n)*64+lane)*8;
  } else {
    r -= 49152;
    int kt = r/768, n = (r/64)%12, lane = r%64;
    const float* w = Wf + (size_t)blk*256*184;
    int col = n*16 + (lane&15);
    #pragma unroll
    for (int j=0;j<8;j++){
      int k = kt*32 + (lane>>4)*8 + j;
      vals[j] = (col < 184) ? w[k*184+col] : 0.f;
    }
    dst += (size_t)OFF_WF*8 + ((size_t)(kt*12+n)*64+lane)*8;
  }
  #pragma unroll
  for (int j=0;j<8;j++) dst[j] = f2bf(vals[j]);
}

// ---- ONE fused kernel: init + all 8 flow blocks ----
__global__ __launch_bounds__(512,2) void flow_k(
  const float* __restrict__ x, const float* __restrict__ params,
  float* __restrict__ zg, float* __restrict__ logdet_g,
  const ushort_t* __restrict__ wpack,
  const float* __restrict__ b_in, const float* __restrict__ b1, const float* __restrict__ b2,
  const float* __restrict__ bc, const float* __restrict__ bf_,
  const float* __restrict__ un_w, const float* __restrict__ un_h, const float* __restrict__ un_d,
  const float* __restrict__ lu_lo, const float* __restrict__ lu_up,
  const float* __restrict__ lu_ud, const float* __restrict__ lu_b,
  const int* __restrict__ perms)
{
  __shared__ ushort_t s_actx[RB][256];   // ctx bf16, swizzled, resident all 8 blocks
  __shared__ ushort_t s_hr[RB][256];     // relu(h)/h bf16, swizzled
  __shared__ ushort_t s_tb[RB][256];     // relu(t1) bf16, swizzled
  __shared__ ushort_t s_azid[RB][32];    // GEMM1 kstep0 A tile, linear
  __shared__ float s_z[RB][16], s_y[RB][16];
  __shared__ float s_zid[RB][8], s_ztr[RB][8];
  __shared__ float s_pb[RB][193];        // spline params (pad 193: bank spread)
  __shared__ float s_ld[RB];
  __shared__ float s_ucw[8][9], s_uch[8][9], s_ud8[8][9];
  __shared__ float s_lulo[120], s_luup[120], s_dg[16], s_slog[16], s_lub[16];
  __shared__ int   s_perm[16];

  const int tid = threadIdx.x;
  const int r0 = blockIdx.x * RB;
  const int wid = tid >> 6, lane = tid & 63;
  const int rA = lane & 15, kA8 = (lane>>4)*8;
  const int n0 = 2*wid;

  // ---- P0 (once): stage x, ctx(f32->bf16 swizzled), zero azid pad, logdet
  {
    int row = tid >> 4, c = tid & 15;
    s_z[row][c] = x[(r0+row)*16 + c];
    const float* src = params + (size_t)(r0+row)*256 + c*16;
    float f[16];
    #pragma unroll
    for (int q=0;q<4;q++){
      float4 v = *(const float4*)(src + q*4);
      f[q*4]=v.x; f[q*4+1]=v.y; f[q*4+2]=v.z; f[q*4+3]=v.w;
    }
    short8v v0, v1;
    #pragma unroll
    for (int j=0;j<8;j++){ v0[j]=(short)f2bf(f[j]); v1[j]=(short)f2bf(f[8+j]); }
    st8(s_actx, row, c*16,   v0);
    st8(s_actx, row, c*16+8, v1);
    for (int i=tid; i<RB*24; i+=512) s_azid[i/24][8+(i%24)] = 0;
    if (tid < RB) s_ld[tid] = 0.f;
  }

  float hreg[2][2][4];

  for (int blk = NBLK-1; blk >= 0; --blk){
    __syncthreads();
    // ---- stage LU params + knots (parallel sections)
    if (tid < 120){
      s_lulo[tid] = lu_lo[blk*120 + tid];
      s_luup[tid] = lu_up[blk*120 + tid];
    } else if (tid >= 128 && tid < 144){
      int c = tid - 128;
      s_perm[c] = perms[blk*16 + c];
      float dg = softplusf(lu_ud[blk*16 + c]) + 0.001f;
      s_dg[c] = dg; s_slog[c] = logf(dg);
      s_lub[c] = lu_b[blk*16 + c];
    } else if (tid >= 192 && tid < 200){
      int k8 = tid - 192;
      const float* uwp = un_w + blk*64 + k8*8;
      const float* uhp = un_h + blk*64 + k8*8;
      const float* udp = un_d + blk*56 + k8*7;
      float m = uwp[0];
      #pragma unroll
      for (int k=1;k<8;k++) m = fmaxf(m, uwp[k]);
      float e[8], s = 0.f;
      #pragma unroll
      for (int k=0;k<8;k++){ e[k]=expf(uwp[k]-m); s+=e[k]; }
      float inv = 1.f/s, c = 0.f;
      s_ucw[k8][0] = -TAILF;
      #pragma unroll
      for (int k=0;k<8;k++){ c += 0.001f + (1.f-0.008f)*e[k]*inv; s_ucw[k8][k+1] = 2.f*TAILF*c - TAILF; }
      s_ucw[k8][8] = TAILF;
      m = uhp[0];
      #pragma unroll
      for (int k=1;k<8;k++) m = fmaxf(m, uhp[k]);
      s = 0.f;
      #pragma unroll
      for (int k=0;k<8;k++){ e[k]=expf(uhp[k]-m); s+=e[k]; }
      inv = 1.f/s; c = 0.f;
      s_uch[k8][0] = -TAILF;
      #pragma unroll
      for (int k=0;k<8;k++){ c += 0.001f + (1.f-0.008f)*e[k]*inv; s_uch[k8][k+1] = 2.f*TAILF*c - TAILF; }
      s_uch[k8][8] = TAILF;
      s_ud8[k8][0] = 1.f; s_ud8[k8][8] = 1.f;
      #pragma unroll
      for (int k=0;k<7;k++) s_ud8[k8][k+1] = 0.001f + softplusf(udp[k]);
    }
    __syncthreads();

    // ---- P1: U apply (permuted input), fully unrolled predicated
    {
      int row = tid >> 4, c = tid & 15;
      float zp[16];
      #pragma unroll
      for (int cc=0;cc<16;cc++) zp[cc] = s_z[row][s_perm[cc]];
      float acc = s_dg[c]*zp[c];
      #pragma unroll
      for (int cc=0;cc<16;cc++)
        if (cc > c) acc += s_luup[c*15 - (c*(c-1))/2 + (cc-c-1)] * zp[cc];
      s_y[row][c] = acc;
    }
    __syncthreads();

    // ---- P2: L apply + bias (overwrite s_z with w)
    {
      int row = tid >> 4, c = tid & 15;
      float yp[16];
      #pragma unroll
      for (int cc=0;cc<16;cc++) yp[cc] = s_y[row][cc];
      float acc = yp[c] + s_lub[c];
      #pragma unroll
      for (int cc=0;cc<16;cc++)
        if (cc < c) acc += s_lulo[(c*(c-1))/2 + cc] * yp[cc];
      s_z[row][c] = acc;
    }
    __syncthreads();

    // ---- P4: uncond spline on even dims
    if (tid < 256){
      int row = tid >> 3, k = tid & 7;
      float o, nl;
      rqs_apply_lds(s_z[row][2*k], s_ucw[k], s_uch[k], s_ud8[k], &o, &nl);
      s_zid[row][k] = o;
      s_ztr[row][k] = s_z[row][2*k+1];
      s_azid[row][k] = f2bf(o);
      float t = nl;
      t += __shfl_xor(t,1); t += __shfl_xor(t,2); t += __shfl_xor(t,4);
      if (k == 0){
        float sl = 0.f;
        #pragma unroll
        for (int c=0;c<16;c++) sl += s_slog[c];
        s_ld[row] += sl + t;
      }
    }
    __syncthreads();

    const short8v* Wpk8 = (const short8v*)(wpack + (size_t)blk*BLK_PACK);

    // ---- G1: h = [zid|ctx] @ W_in + b_in   (KT=9)
    {
      f32x4 acc[2][2];
      #pragma unroll
      for (int f=0;f<2;f++)
        #pragma unroll
        for (int ni=0;ni<2;ni++) acc[f][ni] = (f32x4){0,0,0,0};
      const short8v* Wp = Wpk8;
      float bvv[2] = { b_in[blk*256 + n0*16 + rA], b_in[blk*256 + (n0+1)*16 + rA] };
      short8v B[3][2], A[2][2];
      #pragma unroll
      for (int s=0;s<2;s++){
        B[s][0] = Wp[(size_t)(s*16 + n0    )*64 + lane];
        B[s][1] = Wp[(size_t)(s*16 + n0 + 1)*64 + lane];
      }
      A[0][0] = *(const short8v*)((const char*)s_azid + rA*64 + kA8*2);
      A[0][1] = *(const short8v*)((const char*)s_azid + (rA+16)*64 + kA8*2);
      #pragma unroll
      for (int kt=0; kt<9; ++kt){
        const int sB = kt%3, sA = kt&1;
        if (kt+2 < 9){
          B[(kt+2)%3][0] = Wp[(size_t)((kt+2)*16 + n0    )*64 + lane];
          B[(kt+2)%3][1] = Wp[(size_t)((kt+2)*16 + n0 + 1)*64 + lane];
        }
        if (kt+1 < 9){
          A[(kt+1)&1][0] = ldA(s_actx, rA,    kt*32 + kA8);
          A[(kt+1)&1][1] = ldA(s_actx, rA+16, kt*32 + kA8);
        }
        acc[0][0] = MFMA(A[sA][0], B[sB][0], acc[0][0]);
        acc[1][0] = MFMA(A[sA][1], B[sB][0], acc[1][0]);
        acc[0][1] = MFMA(A[sA][0], B[sB][1], acc[0][1]);
        acc[1][1] = MFMA(A[sA][1], B[sB][1], acc[1][1]);
      }
      #pragma unroll
      for (int ni=0;ni<2;ni++){
        int col = (n0+ni)*16 + rA;
        #pragma unroll
        for (int f=0;f<2;f++)
          #pragma unroll
          for (int r=0;r<4;r++){
            int row = f*16 + (lane>>4)*4 + r;
            float h = acc[f][ni][r] + bvv[ni];
            hreg[f][ni][r] = h;
            stBF(s_hr, row, col, fmaxf(h, 0.f));
          }
      }
    }
    __syncthreads();

    // ---- residual blocks
    for (int j=0;j<NRES;j++){
      // S1: t = relu(relu(h) @ W1 + b1)
      {
        f32x4 acc[2][2];
        #pragma unroll
        for (int f=0;f<2;f++)
          #pragma unroll
          for (int ni=0;ni<2;ni++) acc[f][ni] = (f32x4){0,0,0,0};
        const short8v* Wp = Wpk8 + OFF_WSQ + (size_t)(j*3+0)*8192;
        float bvv[2] = { b1[(blk*2+j)*256 + n0*16 + rA], b1[(blk*2+j)*256 + (n0+1)*16 + rA] };
        short8v B[3][2], A[2][2];
        #pragma unroll
        for (int s=0;s<2;s++){
          B[s][0] = Wp[(size_t)(s*16 + n0    )*64 + lane];
          B[s][1] = Wp[(size_t)(s*16 + n0 + 1)*64 + lane];
        }
        A[0][0] = ldA(s_hr, rA,    kA8);
        A[0][1] = ldA(s_hr, rA+16, kA8);
        #pragma unroll
        for (int kt=0; kt<8; ++kt){
          const int sB = kt%3, sA = kt&1;
          if (kt+2 < 8){
            B[(kt+2)%3][0] = Wp[(size_t)((kt+2)*16 + n0    )*64 + lane];
            B[(kt+2)%3][1] = Wp[(size_t)((kt+2)*16 + n0 + 1)*64 + lane];
          }
          if (kt+1 < 8){
            A[(kt+1)&1][0] = ldA(s_hr, rA,    (kt+1)*32 + kA8);
            A[(kt+1)&1][1] = ldA(s_hr, rA+16, (kt+1)*32 + kA8);
          }
          acc[0][0] = MFMA(A[sA][0], B[sB][0], acc[0][0]);
          acc[1][0] = MFMA(A[sA][1], B[sB][0], acc[1][0]);
          acc[0][1] = MFMA(A[sA][0], B[sB][1], acc[0][1]);
          acc[1][1] = MFMA(A[sA][1], B[sB][1], acc[1][1]);
        }
        #pragma unroll
        for (int ni=0;ni<2;ni++){
          int col = (n0+ni)*16 + rA;
          #pragma unroll
          for (int f=0;f<2;f++)
            #pragma unroll
            for (int r=0;r<4;r++){
              int row = f*16 + (lane>>4)*4 + r;
              stBF(s_tb, row, col, fmaxf(acc[f][ni][r] + bvv[ni], 0.f));
            }
        }
      }
      __syncthreads();
      // S2: h += (t @ W2 + b2) * sigmoid(ctx @ Wc + bc)
      {
        f32x4 acc[2][2], accg[2][2];
        #pragma unroll
        for (int f=0;f<2;f++)
          #pragma unroll
          for (int ni=0;ni<2;ni++){ acc[f][ni]=(f32x4){0,0,0,0}; accg[f][ni]=(f32x4){0,0,0,0}; }
        const short8v* Wv = Wpk8 + OFF_WSQ + (size_t)(j*3+1)*8192;
        const short8v* Wg = Wpk8 + OFF_WSQ + (size_t)(j*3+2)*8192;
        float b2v[2] = { b2[(blk*2+j)*256 + n0*16 + rA], b2[(blk*2+j)*256 + (n0+1)*16 + rA] };
        float bcv[2] = { bc[(blk*2+j)*256 + n0*16 + rA], bc[(blk*2+j)*256 + (n0+1)*16 + rA] };
        short8v Bv[3][2], Bg[3][2], At[2][2], Ac[2][2];
        #pragma unroll
        for (int s=0;s<2;s++){
          Bv[s][0] = Wv[(size_t)(s*16 + n0    )*64 + lane];
          Bv[s][1] = Wv[(size_t)(s*16 + n0 + 1)*64 + lane];
          Bg[s][0] = Wg[(size_t)(s*16 + n0    )*64 + lane];
          Bg[s][1] = Wg[(size_t)(s*16 + n0 + 1)*64 + lane];
        }
        At[0][0] = ldA(s_tb, rA, kA8);   At[0][1] = ldA(s_tb, rA+16, kA8);
        Ac[0][0] = ldA(s_actx, rA, kA8); Ac[0][1] = ldA(s_actx, rA+16, kA8);
        #pragma unroll
        for (int kt=0; kt<8; ++kt){
          const int sB = kt%3, sA = kt&1;
          if (kt+2 < 8){
            Bv[(kt+2)%3][0] = Wv[(size_t)((kt+2)*16 + n0    )*64 + lane];
            Bv[(kt+2)%3][1] = Wv[(size_t)((kt+2)*16 + n0 + 1)*64 + lane];
            Bg[(kt+2)%3][0] = Wg[(size_t)((kt+2)*16 + n0    )*64 + lane];
            Bg[(kt+2)%3][1] = Wg[(size_t)((kt+2)*16 + n0 + 1)*64 + lane];
          }
          if (kt+1 < 8){
            At[(kt+1)&1][0] = ldA(s_tb, rA,    (kt+1)*32 + kA8);
            At[(kt+1)&1][1] = ldA(s_tb, rA+16, (kt+1)*32 + kA8);
            Ac[(kt+1)&1][0] = ldA(s_actx, rA,    (kt+1)*32 + kA8);
            Ac[(kt+1)&1][1] = ldA(s_actx, rA+16, (kt+1)*32 + kA8);
          }
          acc[0][0]  = MFMA(At[sA][0], Bv[sB][0], acc[0][0]);
          acc[1][0]  = MFMA(At[sA][1], Bv[sB][0], acc[1][0]);
          acc[0][1]  = MFMA(At[sA][0], Bv[sB][1], acc[0][1]);
          acc[1][1]  = MFMA(At[sA][1], Bv[sB][1], acc[1][1]);
          accg[0][0] = MFMA(Ac[sA][0], Bg[sB][0], accg[0][0]);
          accg[1][0] = MFMA(Ac[sA][1], Bg[sB][0], accg[1][0]);
          accg[0][1] = MFMA(Ac[sA][0], Bg[sB][1], accg[0][1]);
          accg[1][1] = MFMA(Ac[sA][1], Bg[sB][1], accg[1][1]);
        }
        bool last = (j == NRES-1);
        #pragma unroll
        for (int ni=0;ni<2;ni++){
          int col = (n0+ni)*16 + rA;
          #pragma unroll
          for (int f=0;f<2;f++)
            #pragma unroll
            for (int r=0;r<4;r++){
              int row = f*16 + (lane>>4)*4 + r;
              float v = acc[f][ni][r] + b2v[ni];
              float g = accg[f][ni][r] + bcv[ni];
              float sg = 1.f/(1.f + expf(-g));
              float h = hreg[f][ni][r] + v*sg;
              hreg[f][ni][r] = h;
              stBF(s_hr, row, col, last ? h : fmaxf(h, 0.f));
            }
        }
      }
      __syncthreads();
    }

    // ---- G5: p = h @ Wf + bf  (12 n-blocks of 16; wave: wid and 8+wid(wid<4))
    {
      f32x4 acc[2][2];
      #pragma unroll
      for (int f=0;f<2;f++)
        #pragma unroll
        for (int ni=0;ni<2;ni++) acc[f][ni] = (f32x4){0,0,0,0};
      const short8v* Wp = Wpk8 + OFF_WF;
      const int nA = wid;
      const int nBv = (wid < 4) ? (8 + wid) : wid;
      const int colA = nA*16 + rA;
      const int colB = nBv*16 + rA;
      const bool haveB = (wid < 4);
      float bfv0 = bf_[blk*PDIM + colA];
      float bfv1 = (haveB && colB < PDIM) ? bf_[blk*PDIM + colB] : 0.f;
      short8v B[3][2], A[2][2];
      #pragma unroll
      for (int s=0;s<2;s++){
        B[s][0] = Wp[(size_t)(s*12 + nA )*64 + lane];
        B[s][1] = Wp[(size_t)(s*12 + nBv)*64 + lane];
      }
      A[0][0] = ldA(s_hr, rA,    kA8);
      A[0][1] = ldA(s_hr, rA+16, kA8);
      #pragma unroll
      for (int kt=0; kt<8; ++kt){
        const int sB = kt%3, sA = kt&1;
        if (kt+2 < 8){
          B[(kt+2)%3][0] = Wp[(size_t)((kt+2)*12 + nA )*64 + lane];
          B[(kt+2)%3][1] = Wp[(size_t)((kt+2)*12 + nBv)*64 + lane];
        }
        if (kt+1 < 8){
          A[(kt+1)&1][0] = ldA(s_hr, rA,    (kt+1)*32 + kA8);
          A[(kt+1)&1][1] = ldA(s_hr, rA+16, (kt+1)*32 + kA8);
        }
        acc[0][0] = MFMA(A[sA][0], B[sB][0], acc[0][0]);
        acc[1][0] = MFMA(A[sA][1], B[sB][0], acc[1][0]);
        acc[0][1] = MFMA(A[sA][0], B[sB][1], acc[0][1]);
        acc[1][1] = MFMA(A[sA][1], B[sB][1], acc[1][1]);
      }
      #pragma unroll
      for (int f=0;f<2;f++)
        #pragma unroll
        for (int r=0;r<4;r++){
          int row = f*16 + (lane>>4)*4 + r;
          s_pb[row][colA] = acc[f][0][r] + bfv0;
          if (haveB && colB < PDIM) s_pb[row][colB] = acc[f][1][r] + bfv1;
        }
    }
    __syncthreads();

    // ---- P8: conditional spline on odd dims + reinterleave into s_z
    if (tid < 256){
      int row = tid >> 3, k = tid & 7;
      float pr[23];
      #pragma unroll
      for (int jj=0;jj<23;jj++) pr[jj] = s_pb[row][k*23 + jj];
      float uw[8], uh[8], ud[7];
      #pragma unroll
      for (int b=0;b<8;b++){ uw[b] = pr[b]*0.0625f; uh[b] = pr[8+b]*0.0625f; }
      #pragma unroll
      for (int b=0;b<7;b++) ud[b] = pr[16+b];
      float o, nl;
      rqs_inv1(s_ztr[row][k], uw, uh, ud, &o, &nl);
      s_z[row][2*k]   = s_zid[row][k];
      s_z[row][2*k+1] = o;
      float t = nl;
      t += __shfl_xor(t,1); t += __shfl_xor(t,2); t += __shfl_xor(t,4);
      if (k == 0) s_ld[row] += t;
    }
  }
  __syncthreads();

  // ---- writeback
  {
    int row = tid >> 4, c = tid & 15;
    zg[(r0+row)*16 + c] = s_z[row][c];
  }
  if (tid < RB) logdet_g[r0+tid] = s_ld[tid];
}

__global__ __launch_bounds__(64) void final_k(
  const float* __restrict__ ctx, const float* __restrict__ q0W,
  const float* __restrict__ q0b, const float* __restrict__ z,
  const float* __restrict__ logdet, float* __restrict__ out)
{
  int n = blockIdx.x*64 + threadIdx.x;
  if (n >= N_SAMP) return;
  float acc[2*LAT];
  #pragma unroll
  for (int m=0;m<2*LAT;m++) acc[m] = q0b[m];
  for (int k=0;k<CTXD;k+=4){
    float4 cv = *(const float4*)&ctx[n*CTXD + k];
    #pragma unroll
    for (int m=0;m<2*LAT;m++){
      acc[m] = fmaf(cv.x, q0W[(k+0)*2*LAT + m], acc[m]);
      acc[m] = fmaf(cv.y, q0W[(k+1)*2*LAT + m], acc[m]);
      acc[m] = fmaf(cv.z, q0W[(k+2)*2*LAT + m], acc[m]);
      acc[m] = fmaf(cv.w, q0W[(k+3)*2*LAT + m], acc[m]);
    }
  }
  float s = 0.f;
  #pragma unroll
  for (int dd=0;dd<LAT;dd++){
    float ls = acc[LAT+dd];
    float t = (z[n*LAT+dd] - acc[dd]) * expf(-ls);
    s += ls + 0.5f*t*t;
  }
  float logp = -14.703016531f - s;
  out[n] = -(logp + logdet[n]);
}

extern "C" void kernel_launch(void* const* d_in, const int* in_sizes, int n_in,
                              void* d_out, int out_size, void* d_ws, size_t ws_size,
                              hipStream_t stream)
{
  const float* x      = (const float*)d_in[0];
  const float* params = (const float*)d_in[1];
  const float* W_in   = (const float*)d_in[2];
  const float* b_in   = (const float*)d_in[3];
  const float* W1     = (const float*)d_in[4];
  const float* b1     = (const float*)d_in[5];
  const float* W2     = (const float*)d_in[6];
  const float* b2     = (const float*)d_in[7];
  const float* Wc     = (const float*)d_in[8];
  const float* bc     = (const float*)d_in[9];
  const float* Wf     = (const float*)d_in[10];
  const float* bf_    = (const float*)d_in[11];
  const float* un_w   = (const float*)d_in[12];
  const float* un_h   = (const float*)d_in[13];
  const float* un_d   = (const float*)d_in[14];
  const float* lu_lo  = (const float*)d_in[15];
  const float* lu_up  = (const float*)d_in[16];
  const float* lu_ud  = (const float*)d_in[17];
  const float* lu_b   = (const float*)d_in[18];
  const float* q0W    = (const float*)d_in[19];
  const float* q0b    = (const float*)d_in[20];
  const int*   perms  = (const int*)d_in[21];
  float* out = (float*)d_out;

  float* ws      = (float*)d_ws;
  float* z       = ws;                           // 131072 f
  float* logdet  = z + N_SAMP*LAT;               // 8192 f
  ushort_t* wpk  = (ushort_t*)(logdet + N_SAMP); // 4128768 us

  pack_w_k<<<dim3(2016), 256, 0, stream>>>(W_in, W1, W2, Wc, Wf, wpk);
  flow_k<<<dim3(N_SAMP/RB), 512, 0, stream>>>(
      x, params, z, logdet, wpk,
      b_in, b1, b2, bc, bf_,
      un_w, un_h, un_d, lu_lo, lu_up, lu_ud, lu_b, perms);
  final_k<<<dim3(N_SAMP/64), 64, 0, stream>>>(params, q0W, q0b, z, logdet, out);
}

// Round 4
// 273.303 us; speedup vs baseline: 22.9035x; 1.1798x over previous
//
#include <hip/hip_runtime.h>
#include <math.h>

#define N_SAMP 8192
#define LAT 16
#define DID 8
#define DTR 8
#define KB 8
#define CTXD 256
#define HIDD 256
#define NRES 2
#define NBLK 8
#define PDIM 184
#define TAILF 3.0f
#define RB 32

typedef unsigned short ushort_t;
typedef short short8v __attribute__((ext_vector_type(8)));
typedef float f32x4 __attribute__((ext_vector_type(4)));

// packed-weight sizes (elements)
#define WIN_PACK   73728   // 9 ksteps * 16 nblk * 512
#define WSQ_PACK   65536   // 8 * 16 * 512
#define WF_PACK    49152   // 8 * 12 * 512
#define BLK_PACK   516096  // WIN + 6*WSQ + WF
#define OFF_WSQ    9216    // in short8 units
#define OFF_WF     58368

__device__ __forceinline__ ushort_t f2bf(float f){
  unsigned u = __builtin_bit_cast(unsigned, f);
  unsigned r = (u + 0x7fffu + ((u>>16)&1u)) >> 16;
  return (ushort_t)r;
}
__device__ __forceinline__ float softplusf(float x){
  return (x > 20.0f) ? x : log1pf(expf(x));
}
__device__ __forceinline__ f32x4 MFMA(short8v a, short8v b, f32x4 c){
  return __builtin_amdgcn_mfma_f32_16x16x32_bf16(a, b, c, 0, 0, 0);
}
// swizzled LDS bf16 tile helpers ([RB][256] ushort, 512B rows)
__device__ __forceinline__ short8v ldA(const void* tile, int row, int k){
  int byte = (row*512 + k*2) ^ ((row&7)<<4);
  return *(const short8v*)((const char*)tile + byte);
}
__device__ __forceinline__ void stBF(void* tile, int row, int col, float v){
  int byte = (row*512 + col*2) ^ ((row&7)<<4);
  *(ushort_t*)((char*)tile + byte) = f2bf(v);
}
__device__ __forceinline__ void st8(void* tile, int row, int col, short8v v){
  int byte = (row*512 + col*2) ^ ((row&7)<<4);
  *(short8v*)((char*)tile + byte) = v;
}

// register-version inverse RQS (verified)
__device__ __forceinline__ void rqs_inv1(float x, const float* uw, const float* uh,
                                         const float* ud, float* outp, float* nladp)
{
  const float T = TAILF;
  bool inside = (x >= -T) && (x <= T);
  float cw[KB+1], wv[KB], ch[KB+1], hv[KB], dv[KB+1];
  {
    float m = uw[0];
    #pragma unroll
    for (int k=1;k<KB;k++) m = fmaxf(m, uw[k]);
    float e[KB]; float ssum = 0.f;
    #pragma unroll
    for (int k=0;k<KB;k++){ e[k] = expf(uw[k]-m); ssum += e[k]; }
    float inv = 1.f/ssum; float c = 0.f;
    cw[0] = -T;
    #pragma unroll
    for (int k=0;k<KB;k++){ c += 0.001f + (1.f-0.008f)*e[k]*inv; cw[k+1] = 2.f*T*c - T; }
    cw[KB] = T;
    #pragma unroll
    for (int k=0;k<KB;k++) wv[k] = cw[k+1]-cw[k];
  }
  {
    float m = uh[0];
    #pragma unroll
    for (int k=1;k<KB;k++) m = fmaxf(m, uh[k]);
    float e[KB]; float ssum = 0.f;
    #pragma unroll
    for (int k=0;k<KB;k++){ e[k] = expf(uh[k]-m); ssum += e[k]; }
    float inv = 1.f/ssum; float c = 0.f;
    ch[0] = -T;
    #pragma unroll
    for (int k=0;k<KB;k++){ c += 0.001f + (1.f-0.008f)*e[k]*inv; ch[k+1] = 2.f*T*c - T; }
    ch[KB] = T;
    #pragma unroll
    for (int k=0;k<KB;k++) hv[k] = ch[k+1]-ch[k];
  }
  dv[0] = 1.f; dv[KB] = 1.f;
  #pragma unroll
  for (int k=0;k<KB-1;k++) dv[k+1] = 0.001f + softplusf(ud[k]);

  float xc = fminf(fmaxf(x, -T), T);
  int idx = 0;
  #pragma unroll
  for (int k=1;k<KB;k++) idx += (xc >= ch[k]) ? 1 : 0;

  float icw=cw[0], iw=wv[0], ich=ch[0], ih=hv[0], d0=dv[0], d1=dv[1];
  #pragma unroll
  for (int k=1;k<KB;k++){
    bool sel = (idx==k);
    icw = sel?cw[k]:icw; iw = sel?wv[k]:iw; ich = sel?ch[k]:ich;
    ih = sel?hv[k]:ih; d0 = sel?dv[k]:d0; d1 = sel?dv[k+1]:d1;
  }
  float delta = ih/iw;
  float sq = d0 + d1 - 2.f*delta;
  float yv = xc - ich;
  float aa = yv*sq + ih*(delta-d0);
  float bb = ih*d0 - yv*sq;
  float cc = -delta*yv;
  float disc = fmaxf(bb*bb - 4.f*aa*cc, 0.f);
  float root = 2.f*cc / (-bb - sqrtf(disc));
  float o = root*iw + icw;
  float t1m = root*(1.f-root);
  float den = delta + sq*t1m;
  float num = delta*delta*(d1*root*root + 2.f*delta*t1m + d0*(1.f-root)*(1.f-root));
  float lad = logf(num) - 2.f*logf(den);
  *outp = inside ? o : x;
  *nladp = inside ? -lad : 0.f;
}

// LDS-knot apply (uncond spline)
__device__ __forceinline__ void rqs_apply_lds(float x, const float* cw, const float* ch,
                                              const float* dv, float* outp, float* nladp)
{
  const float T = TAILF;
  bool inside = (x >= -T) && (x <= T);
  float xc = fminf(fmaxf(x, -T), T);
  int idx = 0;
  #pragma unroll
  for (int k=1;k<KB;k++) idx += (xc >= ch[k]) ? 1 : 0;
  float icw = cw[idx], iw = cw[idx+1]-icw;
  float ich = ch[idx], ih = ch[idx+1]-ich;
  float d0 = dv[idx], d1 = dv[idx+1];
  float delta = ih/iw;
  float sq = d0 + d1 - 2.f*delta;
  float yv = xc - ich;
  float aa = yv*sq + ih*(delta-d0);
  float bb = ih*d0 - yv*sq;
  float cc = -delta*yv;
  float disc = fmaxf(bb*bb - 4.f*aa*cc, 0.f);
  float root = 2.f*cc / (-bb - sqrtf(disc));
  float o = root*iw + icw;
  float t1m = root*(1.f-root);
  float den = delta + sq*t1m;
  float num = delta*delta*(d1*root*root + 2.f*delta*t1m + d0*(1.f-root)*(1.f-root));
  float lad = logf(num) - 2.f*logf(den);
  *outp = inside ? o : x;
  *nladp = inside ? -lad : 0.f;
}

// pack all weights into B-fragment-linear bf16 layout (unchanged, verified)
__global__ __launch_bounds__(256) void pack_w_k(
  const float* __restrict__ W_in, const float* __restrict__ W1, const float* __restrict__ W2,
  const float* __restrict__ Wc, const float* __restrict__ Wf, ushort_t* __restrict__ wp)
{
  int t = blockIdx.x*256 + threadIdx.x;
  if (t >= 8*64512) return;
  int blk = t / 64512;
  int r = t % 64512;
  ushort_t* dst = wp + (size_t)blk*BLK_PACK;
  float vals[8];
  if (r < 9216){
    int kt = r/1024, n = (r/64)%16, lane = r%64;
    const float* w = W_in + (size_t)blk*264*256;
    int col = n*16 + (lane&15);
    #pragma unroll
    for (int j=0;j<8;j++){
      int k = kt*32 + (lane>>4)*8 + j;
      vals[j] = (k < 32) ? ((k < 8) ? w[k*256+col] : 0.f) : w[(k-24)*256+col];
    }
    dst += ((size_t)(kt*16+n)*64 + lane)*8;
  } else if ((r -= 9216) < 49152){
    int m = r/8192, rr = r%8192;
    int kt = rr/1024, n = (rr/64)%16, lane = rr%64;
    int j2 = m/3, which = m%3;
    const float* w = (which==0 ? W1 : which==1 ? W2 : Wc) + (size_t)(blk*2+j2)*256*256;
    int col = n*16 + (lane&15);
    #pragma unroll
    for (int j=0;j<8;j++){
      int k = kt*32 + (lane>>4)*8 + j;
      vals[j] = w[k*256+col];
    }
    dst += WIN_PACK + (size_t)m*WSQ_PACK + ((size_t)(kt*16+n)*64+lane)*8;
  } else {
    r -= 49152;
    int kt = r/768, n = (r/64)%12, lane = r%64;
    const float* w = Wf + (size_t)blk*256*184;
    int col = n*16 + (lane&15);
    #pragma unroll
    for (int j=0;j<8;j++){
      int k = kt*32 + (lane>>4)*8 + j;
      vals[j] = (col < 184) ? w[k*184+col] : 0.f;
    }
    dst += (size_t)OFF_WF*8 + ((size_t)(kt*12+n)*64+lane)*8;
  }
  #pragma unroll
  for (int j=0;j<8;j++) dst[j] = f2bf(vals[j]);
}

// ---- ONE fused kernel: init + all 8 flow blocks; 1024 thr = 16 waves ----
__global__ __launch_bounds__(1024,4) void flow_k(
  const float* __restrict__ x, const float* __restrict__ params,
  float* __restrict__ zg, float* __restrict__ logdet_g,
  const ushort_t* __restrict__ wpack,
  const float* __restrict__ b_in, const float* __restrict__ b1, const float* __restrict__ b2,
  const float* __restrict__ bc, const float* __restrict__ bf_,
  const float* __restrict__ un_w, const float* __restrict__ un_h, const float* __restrict__ un_d,
  const float* __restrict__ lu_lo, const float* __restrict__ lu_up,
  const float* __restrict__ lu_ud, const float* __restrict__ lu_b,
  const int* __restrict__ perms)
{
  __shared__ ushort_t s_actx[RB][256];   // ctx bf16, swizzled, resident all 8 blocks
  __shared__ ushort_t s_hr[RB][256];     // relu(h)/h bf16, swizzled
  __shared__ ushort_t s_tb[RB][256];     // relu(t1) bf16, swizzled
  __shared__ ushort_t s_azid[RB][32];    // GEMM1 kstep0 A tile, linear
  __shared__ float s_z[RB][16], s_y[RB][16];
  __shared__ float s_zid[RB][8], s_ztr[RB][8];
  __shared__ float s_pb[RB][193];        // spline params (pad 193)
  __shared__ float s_ld[RB];
  __shared__ float s_ucw[8][9], s_uch[8][9], s_ud8[8][9];
  __shared__ float s_lulo[120], s_luup[120], s_dg[16], s_slog[16], s_lub[16];
  __shared__ int   s_perm[16];

  const int tid = threadIdx.x;
  const int r0 = blockIdx.x * RB;
  const int wid = tid >> 6, lane = tid & 63;
  const int rA = lane & 15, kA8 = (lane>>4)*8;

  // staging helper thread-ranges use t2 = tid - 512 (so it can co-run with P8)
  auto stage_params = [&](int blk, int t2){
    if (t2 >= 0 && t2 < 120){
      s_lulo[t2] = lu_lo[blk*120 + t2];
      s_luup[t2] = lu_up[blk*120 + t2];
    } else if (t2 >= 128 && t2 < 144){
      int c = t2 - 128;
      s_perm[c] = perms[blk*16 + c];
      float dg = softplusf(lu_ud[blk*16 + c]) + 0.001f;
      s_dg[c] = dg; s_slog[c] = logf(dg);
      s_lub[c] = lu_b[blk*16 + c];
    } else if (t2 >= 192 && t2 < 200){
      int k8 = t2 - 192;
      const float* uwp = un_w + blk*64 + k8*8;
      const float* uhp = un_h + blk*64 + k8*8;
      const float* udp = un_d + blk*56 + k8*7;
      float m = uwp[0];
      #pragma unroll
      for (int k=1;k<8;k++) m = fmaxf(m, uwp[k]);
      float e[8], s = 0.f;
      #pragma unroll
      for (int k=0;k<8;k++){ e[k]=expf(uwp[k]-m); s+=e[k]; }
      float inv = 1.f/s, c = 0.f;
      s_ucw[k8][0] = -TAILF;
      #pragma unroll
      for (int k=0;k<8;k++){ c += 0.001f + (1.f-0.008f)*e[k]*inv; s_ucw[k8][k+1] = 2.f*TAILF*c - TAILF; }
      s_ucw[k8][8] = TAILF;
      m = uhp[0];
      #pragma unroll
      for (int k=1;k<8;k++) m = fmaxf(m, uhp[k]);
      s = 0.f;
      #pragma unroll
      for (int k=0;k<8;k++){ e[k]=expf(uhp[k]-m); s+=e[k]; }
      inv = 1.f/s; c = 0.f;
      s_uch[k8][0] = -TAILF;
      #pragma unroll
      for (int k=0;k<8;k++){ c += 0.001f + (1.f-0.008f)*e[k]*inv; s_uch[k8][k+1] = 2.f*TAILF*c - TAILF; }
      s_uch[k8][8] = TAILF;
      s_ud8[k8][0] = 1.f; s_ud8[k8][8] = 1.f;
      #pragma unroll
      for (int k=0;k<7;k++) s_ud8[k8][k+1] = 0.001f + softplusf(udp[k]);
    }
  };

  // ---- P0 (once): stage x, ctx(f32->bf16 swizzled), azid pad, logdet, blk7 params
  if (tid < 512){
    int row = tid >> 4, c = tid & 15;
    s_z[row][c] = x[(r0+row)*16 + c];
    const float* src = params + (size_t)(r0+row)*256 + c*16;
    float f[16];
    #pragma unroll
    for (int q=0;q<4;q++){
      float4 v = *(const float4*)(src + q*4);
      f[q*4]=v.x; f[q*4+1]=v.y; f[q*4+2]=v.z; f[q*4+3]=v.w;
    }
    short8v v0, v1;
    #pragma unroll
    for (int j=0;j<8;j++){ v0[j]=(short)f2bf(f[j]); v1[j]=(short)f2bf(f[8+j]); }
    st8(s_actx, row, c*16,   v0);
    st8(s_actx, row, c*16+8, v1);
    if (tid < RB) s_ld[tid] = 0.f;
  } else {
    stage_params(NBLK-1, tid - 512);
  }
  for (int i=tid; i<RB*24; i+=1024) s_azid[i/24][8+(i%24)] = 0;

  float hreg[2][4];

  for (int blk = NBLK-1; blk >= 0; --blk){
    __syncthreads();

    // ---- P1: U apply (permuted input)
    if (tid < 512){
      int row = tid >> 4, c = tid & 15;
      float zp[16];
      #pragma unroll
      for (int cc=0;cc<16;cc++) zp[cc] = s_z[row][s_perm[cc]];
      float acc = s_dg[c]*zp[c];
      #pragma unroll
      for (int cc=0;cc<16;cc++)
        if (cc > c) acc += s_luup[c*15 - (c*(c-1))/2 + (cc-c-1)] * zp[cc];
      s_y[row][c] = acc;
    }
    __syncthreads();

    // ---- P2: L apply + bias (overwrite s_z with w)
    if (tid < 512){
      int row = tid >> 4, c = tid & 15;
      float yp[16];
      #pragma unroll
      for (int cc=0;cc<16;cc++) yp[cc] = s_y[row][cc];
      float acc = yp[c] + s_lub[c];
      #pragma unroll
      for (int cc=0;cc<16;cc++)
        if (cc < c) acc += s_lulo[(c*(c-1))/2 + cc] * yp[cc];
      s_z[row][c] = acc;
    }
    __syncthreads();

    // ---- P4: uncond spline on even dims
    if (tid < 256){
      int row = tid >> 3, k = tid & 7;
      float o, nl;
      rqs_apply_lds(s_z[row][2*k], s_ucw[k], s_uch[k], s_ud8[k], &o, &nl);
      s_zid[row][k] = o;
      s_ztr[row][k] = s_z[row][2*k+1];
      s_azid[row][k] = f2bf(o);
      float t = nl;
      t += __shfl_xor(t,1); t += __shfl_xor(t,2); t += __shfl_xor(t,4);
      if (k == 0){
        float sl = 0.f;
        #pragma unroll
        for (int c=0;c<16;c++) sl += s_slog[c];
        s_ld[row] += sl + t;
      }
    }
    __syncthreads();

    const short8v* Wpk8 = (const short8v*)(wpack + (size_t)blk*BLK_PACK);

    // ---- G1: h = [zid|ctx] @ W_in + b_in   (KT=9; wave owns nblk wid)
    {
      f32x4 acc[2];
      acc[0] = (f32x4){0,0,0,0}; acc[1] = (f32x4){0,0,0,0};
      const short8v* Wp = Wpk8;
      float bvv = b_in[blk*256 + wid*16 + rA];
      short8v B[3], A[2][2];
      B[0] = Wp[(size_t)(0*16 + wid)*64 + lane];
      B[1] = Wp[(size_t)(1*16 + wid)*64 + lane];
      A[0][0] = *(const short8v*)((const char*)s_azid + rA*64 + kA8*2);
      A[0][1] = *(const short8v*)((const char*)s_azid + (rA+16)*64 + kA8*2);
      #pragma unroll
      for (int kt=0; kt<9; ++kt){
        const int sB = kt%3, sA = kt&1;
        if (kt+2 < 9) B[(kt+2)%3] = Wp[(size_t)((kt+2)*16 + wid)*64 + lane];
        if (kt+1 < 9){
          A[(kt+1)&1][0] = ldA(s_actx, rA,    kt*32 + kA8);
          A[(kt+1)&1][1] = ldA(s_actx, rA+16, kt*32 + kA8);
        }
        acc[0] = MFMA(A[sA][0], B[sB], acc[0]);
        acc[1] = MFMA(A[sA][1], B[sB], acc[1]);
      }
      int col = wid*16 + rA;
      #pragma unroll
      for (int f=0;f<2;f++)
        #pragma unroll
        for (int r=0;r<4;r++){
          int row = f*16 + (lane>>4)*4 + r;
          float h = acc[f][r] + bvv;
          hreg[f][r] = h;
          stBF(s_hr, row, col, fmaxf(h, 0.f));
        }
    }
    __syncthreads();

    // ---- residual blocks
    for (int j=0;j<NRES;j++){
      // S1: t = relu(relu(h) @ W1 + b1)
      {
        f32x4 acc[2];
        acc[0] = (f32x4){0,0,0,0}; acc[1] = (f32x4){0,0,0,0};
        const short8v* Wp = Wpk8 + OFF_WSQ + (size_t)(j*3+0)*8192;
        float bvv = b1[(blk*2+j)*256 + wid*16 + rA];
        short8v B[3], A[2][2];
        B[0] = Wp[(size_t)(0*16 + wid)*64 + lane];
        B[1] = Wp[(size_t)(1*16 + wid)*64 + lane];
        A[0][0] = ldA(s_hr, rA,    kA8);
        A[0][1] = ldA(s_hr, rA+16, kA8);
        #pragma unroll
        for (int kt=0; kt<8; ++kt){
          const int sB = kt%3, sA = kt&1;
          if (kt+2 < 8) B[(kt+2)%3] = Wp[(size_t)((kt+2)*16 + wid)*64 + lane];
          if (kt+1 < 8){
            A[(kt+1)&1][0] = ldA(s_hr, rA,    (kt+1)*32 + kA8);
            A[(kt+1)&1][1] = ldA(s_hr, rA+16, (kt+1)*32 + kA8);
          }
          acc[0] = MFMA(A[sA][0], B[sB], acc[0]);
          acc[1] = MFMA(A[sA][1], B[sB], acc[1]);
        }
        int col = wid*16 + rA;
        #pragma unroll
        for (int f=0;f<2;f++)
          #pragma unroll
          for (int r=0;r<4;r++){
            int row = f*16 + (lane>>4)*4 + r;
            stBF(s_tb, row, col, fmaxf(acc[f][r] + bvv, 0.f));
          }
      }
      __syncthreads();
      // S2: h += (t @ W2 + b2) * sigmoid(ctx @ Wc + bc)
      {
        f32x4 acc[2], accg[2];
        acc[0]=(f32x4){0,0,0,0}; acc[1]=(f32x4){0,0,0,0};
        accg[0]=(f32x4){0,0,0,0}; accg[1]=(f32x4){0,0,0,0};
        const short8v* Wv = Wpk8 + OFF_WSQ + (size_t)(j*3+1)*8192;
        const short8v* Wg = Wpk8 + OFF_WSQ + (size_t)(j*3+2)*8192;
        float b2v = b2[(blk*2+j)*256 + wid*16 + rA];
        float bcv = bc[(blk*2+j)*256 + wid*16 + rA];
        short8v Bv[3], Bg[3], At[2][2], Ac[2][2];
        Bv[0] = Wv[(size_t)(0*16 + wid)*64 + lane];
        Bv[1] = Wv[(size_t)(1*16 + wid)*64 + lane];
        Bg[0] = Wg[(size_t)(0*16 + wid)*64 + lane];
        Bg[1] = Wg[(size_t)(1*16 + wid)*64 + lane];
        At[0][0] = ldA(s_tb, rA, kA8);   At[0][1] = ldA(s_tb, rA+16, kA8);
        Ac[0][0] = ldA(s_actx, rA, kA8); Ac[0][1] = ldA(s_actx, rA+16, kA8);
        #pragma unroll
        for (int kt=0; kt<8; ++kt){
          const int sB = kt%3, sA = kt&1;
          if (kt+2 < 8){
            Bv[(kt+2)%3] = Wv[(size_t)((kt+2)*16 + wid)*64 + lane];
            Bg[(kt+2)%3] = Wg[(size_t)((kt+2)*16 + wid)*64 + lane];
          }
          if (kt+1 < 8){
            At[(kt+1)&1][0] = ldA(s_tb, rA,    (kt+1)*32 + kA8);
            At[(kt+1)&1][1] = ldA(s_tb, rA+16, (kt+1)*32 + kA8);
            Ac[(kt+1)&1][0] = ldA(s_actx, rA,    (kt+1)*32 + kA8);
            Ac[(kt+1)&1][1] = ldA(s_actx, rA+16, (kt+1)*32 + kA8);
          }
          acc[0]  = MFMA(At[sA][0], Bv[sB], acc[0]);
          acc[1]  = MFMA(At[sA][1], Bv[sB], acc[1]);
          accg[0] = MFMA(Ac[sA][0], Bg[sB], accg[0]);
          accg[1] = MFMA(Ac[sA][1], Bg[sB], accg[1]);
        }
        bool last = (j == NRES-1);
        int col = wid*16 + rA;
        #pragma unroll
        for (int f=0;f<2;f++)
          #pragma unroll
          for (int r=0;r<4;r++){
            int row = f*16 + (lane>>4)*4 + r;
            float v = acc[f][r] + b2v;
            float g = accg[f][r] + bcv;
            float sg = 1.f/(1.f + expf(-g));
            float h = hreg[f][r] + v*sg;
            hreg[f][r] = h;
            stBF(s_hr, row, col, last ? h : fmaxf(h, 0.f));
          }
      }
      __syncthreads();
    }

    // ---- G5: p = h @ Wf + bf  (12 n-blocks; waves 0-11)
    if (wid < 12){
      f32x4 acc[2];
      acc[0] = (f32x4){0,0,0,0}; acc[1] = (f32x4){0,0,0,0};
      const short8v* Wp = Wpk8 + OFF_WF;
      int col = wid*16 + rA;
      float bfv = (col < PDIM) ? bf_[blk*PDIM + col] : 0.f;
      short8v B[3], A[2][2];
      B[0] = Wp[(size_t)(0*12 + wid)*64 + lane];
      B[1] = Wp[(size_t)(1*12 + wid)*64 + lane];
      A[0][0] = ldA(s_hr, rA,    kA8);
      A[0][1] = ldA(s_hr, rA+16, kA8);
      #pragma unroll
      for (int kt=0; kt<8; ++kt){
        const int sB = kt%3, sA = kt&1;
        if (kt+2 < 8) B[(kt+2)%3] = Wp[(size_t)((kt+2)*12 + wid)*64 + lane];
        if (kt+1 < 8){
          A[(kt+1)&1][0] = ldA(s_hr, rA,    (kt+1)*32 + kA8);
          A[(kt+1)&1][1] = ldA(s_hr, rA+16, (kt+1)*32 + kA8);
        }
        acc[0] = MFMA(A[sA][0], B[sB], acc[0]);
        acc[1] = MFMA(A[sA][1], B[sB], acc[1]);
      }
      if (col < PDIM){
        #pragma unroll
        for (int f=0;f<2;f++)
          #pragma unroll
          for (int r=0;r<4;r++){
            int row = f*16 + (lane>>4)*4 + r;
            s_pb[row][col] = acc[f][r] + bfv;
          }
      }
    }
    __syncthreads();

    // ---- P8: conditional spline on odd dims + reinterleave; co-stage next blk
    if (tid < 256){
      int row = tid >> 3, k = tid & 7;
      float pr[23];
      #pragma unroll
      for (int jj=0;jj<23;jj++) pr[jj] = s_pb[row][k*23 + jj];
      float uw[8], uh[8], ud[7];
      #pragma unroll
      for (int b=0;b<8;b++){ uw[b] = pr[b]*0.0625f; uh[b] = pr[8+b]*0.0625f; }
      #pragma unroll
      for (int b=0;b<7;b++) ud[b] = pr[16+b];
      float o, nl;
      rqs_inv1(s_ztr[row][k], uw, uh, ud, &o, &nl);
      s_z[row][2*k]   = s_zid[row][k];
      s_z[row][2*k+1] = o;
      float t = nl;
      t += __shfl_xor(t,1); t += __shfl_xor(t,2); t += __shfl_xor(t,4);
      if (k == 0) s_ld[row] += t;
    } else if (blk > 0){
      stage_params(blk-1, tid - 512);
    }
  }
  __syncthreads();

  // ---- writeback
  if (tid < 512){
    int row = tid >> 4, c = tid & 15;
    zg[(r0+row)*16 + c] = s_z[row][c];
    if (tid < RB) logdet_g[r0+tid] = s_ld[tid];
  }
}

__global__ __launch_bounds__(64) void final_k(
  const float* __restrict__ ctx, const float* __restrict__ q0W,
  const float* __restrict__ q0b, const float* __restrict__ z,
  const float* __restrict__ logdet, float* __restrict__ out)
{
  int n = blockIdx.x*64 + threadIdx.x;
  if (n >= N_SAMP) return;
  float acc[2*LAT];
  #pragma unroll
  for (int m=0;m<2*LAT;m++) acc[m] = q0b[m];
  for (int k=0;k<CTXD;k+=4){
    float4 cv = *(const float4*)&ctx[n*CTXD + k];
    #pragma unroll
    for (int m=0;m<2*LAT;m++){
      acc[m] = fmaf(cv.x, q0W[(k+0)*2*LAT + m], acc[m]);
      acc[m] = fmaf(cv.y, q0W[(k+1)*2*LAT + m], acc[m]);
      acc[m] = fmaf(cv.z, q0W[(k+2)*2*LAT + m], acc[m]);
      acc[m] = fmaf(cv.w, q0W[(k+3)*2*LAT + m], acc[m]);
    }
  }
  float s = 0.f;
  #pragma unroll
  for (int dd=0;dd<LAT;dd++){
    float ls = acc[LAT+dd];
    float t = (z[n*LAT+dd] - acc[dd]) * expf(-ls);
    s += ls + 0.5f*t*t;
  }
  float logp = -14.703016531f - s;
  out[n] = -(logp + logdet[n]);
}

extern "C" void kernel_launch(void* const* d_in, const int* in_sizes, int n_in,
                              void* d_out, int out_size, void* d_ws, size_t ws_size,
                              hipStream_t stream)
{
  const float* x      = (const float*)d_in[0];
  const float* params = (const float*)d_in[1];
  const float* W_in   = (const float*)d_in[2];
  const float* b_in   = (const float*)d_in[3];
  const float* W1     = (const float*)d_in[4];
  const float* b1     = (const float*)d_in[5];
  const float* W2     = (const float*)d_in[6];
  const float* b2     = (const float*)d_in[7];
  const float* Wc     = (const float*)d_in[8];
  const float* bc     = (const float*)d_in[9];
  const float* Wf     = (const float*)d_in[10];
  const float* bf_    = (const float*)d_in[11];
  const float* un_w   = (const float*)d_in[12];
  const float* un_h   = (const float*)d_in[13];
  const float* un_d   = (const float*)d_in[14];
  const float* lu_lo  = (const float*)d_in[15];
  const float* lu_up  = (const float*)d_in[16];
  const float* lu_ud  = (const float*)d_in[17];
  const float* lu_b   = (const float*)d_in[18];
  const float* q0W    = (const float*)d_in[19];
  const float* q0b    = (const float*)d_in[20];
  const int*   perms  = (const int*)d_in[21];
  float* out = (float*)d_out;

  float* ws      = (float*)d_ws;
  float* z       = ws;                           // 131072 f
  float* logdet  = z + N_SAMP*LAT;               // 8192 f
  ushort_t* wpk  = (ushort_t*)(logdet + N_SAMP); // 4128768 us

  pack_w_k<<<dim3(2016), 256, 0, stream>>>(W_in, W1, W2, Wc, Wf, wpk);
  flow_k<<<dim3(N_SAMP/RB), 1024, 0, stream>>>(
      x, params, z, logdet, wpk,
      b_in, b1, b2, bc, bf_,
      un_w, un_h, un_d, lu_lo, lu_up, lu_ud, lu_b, perms);
  final_k<<<dim3(N_SAMP/64), 64, 0, stream>>>(params, q0W, q0b, z, logdet, out);
}